// Round 1
// baseline (1081.581 us; speedup 1.0000x reference)
//
#include <hip/hip_runtime.h>
#include <math.h>

#define SEQ 2048
#define ND  1024
#define NH  16
#define HD  64
#define NPOSN 64

__device__ __forceinline__ float lane_bcast(float v, int l) {
  return __int_as_float(__builtin_amdgcn_readlane(__float_as_int(v), l));
}

// C[M,N] = X[M,K] @ W[N,K]^T + bias[N]
// MODE 0: plain row-major out. MODE 1: head layout out[h][m][d], h=n>>6, d=n&63.
template <int MODE>
__global__ __launch_bounds__(256)
void gemm_bt(const float* __restrict__ X, const float* __restrict__ W,
             const float* __restrict__ bias, float* __restrict__ C,
             int M, int N, int K) {
  __shared__ __align__(16) float Xs[16][68];
  __shared__ __align__(16) float Ws[16][68];
  const int t  = threadIdx.x;
  const int tx = t & 15, ty = t >> 4;
  const int m0 = blockIdx.x * 64, n0 = blockIdx.y * 64;
  const int r  = t >> 2;
  const int c4 = (t & 3) << 2;
  const float* Xp = X + (size_t)(m0 + r) * K + c4;
  const float* Wp = W + (size_t)(n0 + r) * K + c4;
  float acc[4][4] = {};
  for (int k0 = 0; k0 < K; k0 += 16) {
    float4 xv = *(const float4*)(Xp + k0);
    float4 wv = *(const float4*)(Wp + k0);
    __syncthreads();  // protect previous iteration's reads
    Xs[c4 + 0][r] = xv.x; Xs[c4 + 1][r] = xv.y;
    Xs[c4 + 2][r] = xv.z; Xs[c4 + 3][r] = xv.w;
    Ws[c4 + 0][r] = wv.x; Ws[c4 + 1][r] = wv.y;
    Ws[c4 + 2][r] = wv.z; Ws[c4 + 3][r] = wv.w;
    __syncthreads();
#pragma unroll
    for (int k = 0; k < 16; ++k) {
      const float4 xr = *(const float4*)&Xs[k][ty << 2];
      const float4 wr = *(const float4*)&Ws[k][tx << 2];
      const float xa[4] = {xr.x, xr.y, xr.z, xr.w};
      const float wa[4] = {wr.x, wr.y, wr.z, wr.w};
#pragma unroll
      for (int i = 0; i < 4; ++i)
#pragma unroll
        for (int j = 0; j < 4; ++j) acc[i][j] += xa[i] * wa[j];
    }
  }
#pragma unroll
  for (int i = 0; i < 4; ++i) {
    const int m = m0 + (ty << 2) + i;
#pragma unroll
    for (int j = 0; j < 4; ++j) {
      const int n = n0 + (tx << 2) + j;
      const float v = acc[i][j] + bias[n];
      if (MODE == 0) {
        C[(size_t)m * N + n] = v;
      } else {
        const int h = n >> 6, d = n & 63;
        C[((size_t)h * SEQ + m) * HD + d] = v;
      }
    }
  }
}

// Flash-style attention with CoPE. Key tiles processed LAST->FIRST so the
// reverse-cumsum of gates is a running carry; online softmax is order-free.
// Block: 256 thr = 4 waves; each wave owns 4 q-rows; block shares K/V tile.
__global__ __launch_bounds__(256)
void cope_attn(const float* __restrict__ Qh, const float* __restrict__ Kh,
               const float* __restrict__ Vh, const float* __restrict__ pe,
               float* __restrict__ AO) {
  __shared__ float Kt[64][65];   // stride 65: conflict-free scalar reads
  __shared__ float Vt[64][65];
  __shared__ float lis[16][64];  // logits_int rows (one per q-row in block)
  const int t    = threadIdx.x;
  const int lane = t & 63;
  const int w    = t >> 6;                 // wave id 0..3
  const int h    = blockIdx.y;
  const int qbase = blockIdx.x * 16 + w * 4;

  // q rows in registers: lane holds q[row][d=lane]
  float qreg[4];
#pragma unroll
  for (int rr = 0; rr < 4; ++rr)
    qreg[rr] = Qh[((size_t)h * SEQ + qbase + rr) * HD + lane];

  // logits_int[row][n=lane] = sum_d q[row][d] * pe[d][n]
  float li[4] = {0.f, 0.f, 0.f, 0.f};
  for (int d = 0; d < 64; ++d) {
    const float pv = pe[d * NPOSN + lane];
#pragma unroll
    for (int rr = 0; rr < 4; ++rr) li[rr] += lane_bcast(qreg[rr], d) * pv;
  }
#pragma unroll
  for (int rr = 0; rr < 4; ++rr) lis[w * 4 + rr][lane] = li[rr];

  float mrow[4]  = {-1e30f, -1e30f, -1e30f, -1e30f};
  float lrow[4]  = {0.f, 0.f, 0.f, 0.f};
  float carry[4] = {0.f, 0.f, 0.f, 0.f};
  float acc[4]   = {0.f, 0.f, 0.f, 0.f};

  for (int kt = (SEQ / 64) - 1; kt >= 0; --kt) {
    const int k0 = kt * 64;
    __syncthreads();  // also orders the lis writes before first use
#pragma unroll
    for (int i = 0; i < 4; ++i) {
      const int lin = t + i * 256;          // 0..1023 float4 units
      const int row = lin >> 4, cc = (lin & 15) << 2;
      const float4 kv = *(const float4*)(Kh + ((size_t)h * SEQ + k0 + row) * HD + cc);
      Kt[row][cc + 0] = kv.x; Kt[row][cc + 1] = kv.y;
      Kt[row][cc + 2] = kv.z; Kt[row][cc + 3] = kv.w;
      const float4 vv = *(const float4*)(Vh + ((size_t)h * SEQ + k0 + row) * HD + cc);
      Vt[row][cc + 0] = vv.x; Vt[row][cc + 1] = vv.y;
      Vt[row][cc + 2] = vv.z; Vt[row][cc + 3] = vv.w;
    }
    __syncthreads();

    // QK^T: lane = key j; Kt[lane][d] conflict-free (stride 65 => 2-way, free)
    float sv[4] = {0.f, 0.f, 0.f, 0.f};
#pragma unroll
    for (int d = 0; d < 64; ++d) {
      const float kd = Kt[lane][d];
#pragma unroll
      for (int rr = 0; rr < 4; ++rr) sv[rr] += lane_bcast(qreg[rr], d) * kd;
    }

    float p4[4], scl[4];
#pragma unroll
    for (int rr = 0; rr < 4; ++rr) {
      const float s = sv[rr] * 0.125f;           // / sqrt(64)
      const float g = 1.0f / (1.0f + __expf(-s));
      // inclusive suffix-sum across 64 lanes
      float gs = g;
#pragma unroll
      for (int off = 1; off < 64; off <<= 1) {
        const float tt = __shfl_down(gs, off, 64);
        gs += (lane + off < 64) ? tt : 0.0f;
      }
      const float tot = lane_bcast(gs, 0);
      float pos = carry[rr] + gs;                 // suffix over ALL keys >= this one
      carry[rr] += tot;
      pos = fminf(pos, 63.0f);
      const float pf = floorf(pos);
      const float wq = pos - pf;
      const int fi = (int)pf;
      const int ci = (int)ceilf(pos);
      const float cope = lis[w * 4 + rr][ci] * wq + lis[w * 4 + rr][fi] * (1.0f - wq);
      const float a = s + cope;
      // online softmax
      float mt = a;
#pragma unroll
      for (int off = 32; off > 0; off >>= 1) mt = fmaxf(mt, __shfl_xor(mt, off, 64));
      const float nm = fmaxf(mrow[rr], mt);
      const float sc = __expf(mrow[rr] - nm);
      const float p  = __expf(a - nm);
      float ps = p;
#pragma unroll
      for (int off = 32; off > 0; off >>= 1) ps += __shfl_xor(ps, off, 64);
      lrow[rr] = lrow[rr] * sc + ps;
      mrow[rr] = nm;
      p4[rr]  = p;
      scl[rr] = sc;
    }

    // PV: lane = output dim d; Vt[j][lane] conflict-free
#pragma unroll
    for (int rr = 0; rr < 4; ++rr) acc[rr] *= scl[rr];
#pragma unroll
    for (int j = 0; j < 64; ++j) {
      const float vj = Vt[j][lane];
#pragma unroll
      for (int rr = 0; rr < 4; ++rr) acc[rr] += lane_bcast(p4[rr], j) * vj;
    }
  }

#pragma unroll
  for (int rr = 0; rr < 4; ++rr)
    AO[(size_t)(qbase + rr) * ND + h * HD + lane] = acc[rr] / lrow[rr];
}

extern "C" void kernel_launch(void* const* d_in, const int* in_sizes, int n_in,
                              void* d_out, int out_size, void* d_ws, size_t ws_size,
                              hipStream_t stream) {
  (void)in_sizes; (void)n_in; (void)out_size; (void)ws_size;
  const float* q    = (const float*)d_in[0];
  const float* k    = (const float*)d_in[1];
  const float* v    = (const float*)d_in[2];
  const float* Wq_w = (const float*)d_in[3];
  const float* Wq_b = (const float*)d_in[4];
  const float* Wk_w = (const float*)d_in[5];
  const float* Wk_b = (const float*)d_in[6];
  const float* Wv_w = (const float*)d_in[7];
  const float* Wv_b = (const float*)d_in[8];
  const float* Wo_w = (const float*)d_in[9];
  const float* Wo_b = (const float*)d_in[10];
  const float* pe   = (const float*)d_in[11];
  float* out = (float*)d_out;

  const size_t per = (size_t)NH * SEQ * HD;   // 2M floats
  float* Qh = (float*)d_ws;
  float* Kh = Qh + per;
  float* Vh = Kh + per;
  float* AO = Vh + per;                        // [SEQ][ND]

  dim3 gblk(256);
  dim3 ggrd(SEQ / 64, ND / 64);
  gemm_bt<1><<<ggrd, gblk, 0, stream>>>(q, Wq_w, Wq_b, Qh, SEQ, ND, ND);
  gemm_bt<1><<<ggrd, gblk, 0, stream>>>(k, Wk_w, Wk_b, Kh, SEQ, ND, ND);
  gemm_bt<1><<<ggrd, gblk, 0, stream>>>(v, Wv_w, Wv_b, Vh, SEQ, ND, ND);

  dim3 ablk(256);
  dim3 agrd(SEQ / 16, NH);
  cope_attn<<<agrd, ablk, 0, stream>>>(Qh, Kh, Vh, pe, AO);

  gemm_bt<0><<<ggrd, gblk, 0, stream>>>(AO, Wo_w, Wo_b, out, SEQ, ND, ND);
}

// Round 3
// 531.985 us; speedup vs baseline: 2.0331x; 2.0331x over previous
//
#include <hip/hip_runtime.h>
#include <hip/hip_bf16.h>
#include <math.h>

#define SEQ 2048
#define ND  1024
#define NH  16
#define HD  64
#define NPOSN 64

typedef short short8 __attribute__((ext_vector_type(8)));
typedef short short4v __attribute__((ext_vector_type(4)));
typedef float floatx4 __attribute__((ext_vector_type(4)));

#define MFMA16(A, B, C) __builtin_amdgcn_mfma_f32_16x16x32_bf16((A), (B), (C), 0, 0, 0)

#define ASYNC16(gp, lp)                                                                     \
  __builtin_amdgcn_global_load_lds((const __attribute__((address_space(1))) unsigned int*)(gp), \
                                   (__attribute__((address_space(3))) unsigned int*)(lp), 16, 0, 0)

__device__ __forceinline__ short f2bf(float x) {
  __hip_bfloat16 h = __float2bfloat16(x);
  return *reinterpret_cast<short*>(&h);
}
__device__ __forceinline__ float bf2f(short s) {
  __hip_bfloat16 h = *reinterpret_cast<__hip_bfloat16*>(&s);
  return __bfloat162float(h);
}
__device__ __forceinline__ float lane_bcast(float v, int l) {
  return __int_as_float(__builtin_amdgcn_readlane(__float_as_int(v), l));
}

// ---------------------------------------------------------------------------
// fp32 -> split bf16 rows of 3072.
// wmode 0 (X side): [hi | lo | hi]
// wmode 1 (W side): [hi | hi | lo]
// Dot over 3072 = hi·hi + lo·hi + hi·lo  (error ~2^-18 relative)
// ---------------------------------------------------------------------------
__global__ __launch_bounds__(256)
void split3_convert(const float* __restrict__ in, short* __restrict__ out,
                    int total4, int wmode) {
  int idx = blockIdx.x * 256 + threadIdx.x;
  if (idx >= total4) return;
  int r = idx >> 8;            // 1024 cols / 4 per thread = 256 groups per row
  int c = (idx & 255) << 2;
  float4 v = *(const float4*)(in + (size_t)r * 1024 + c);
  short4v hi, lo;
  hi.x = f2bf(v.x); lo.x = f2bf(v.x - bf2f(hi.x));
  hi.y = f2bf(v.y); lo.y = f2bf(v.y - bf2f(hi.y));
  hi.z = f2bf(v.z); lo.z = f2bf(v.z - bf2f(hi.z));
  hi.w = f2bf(v.w); lo.w = f2bf(v.w - bf2f(hi.w));
  *(short4v*)(out + (size_t)r * 3072 + c) = hi;
  if (wmode == 0) {
    *(short4v*)(out + (size_t)r * 3072 + 1024 + c) = lo;
    *(short4v*)(out + (size_t)r * 3072 + 2048 + c) = hi;
  } else {
    *(short4v*)(out + (size_t)r * 3072 + 1024 + c) = hi;
    *(short4v*)(out + (size_t)r * 3072 + 2048 + c) = lo;
  }
}

__global__ __launch_bounds__(256)
void pe_transpose(const float* __restrict__ pe, short* __restrict__ peT) {
  for (int i = threadIdx.x; i < 4096; i += 256) {
    int n = i >> 6, d = i & 63;
    peT[n * 64 + d] = f2bf(pe[d * 64 + n]);   // peT[npos][d]
  }
}

// ---------------------------------------------------------------------------
// Split-bf16 MFMA GEMM: C[M,N] = Xs[M,3072] · Ws[N,3072]^T + bias
// mode 0: fp32 out [M][1024]
// mode 1: head split bf16: o0/o1 = hi/lo at [h][m][64]
// mode 2: head transposed split: hi/lo at [h][64][m]
// ---------------------------------------------------------------------------
struct GArg {
  const short* X; const short* W; const float* bias;
  void* o0; void* o1; int mode;
};

__global__ __launch_bounds__(256)
void gemm_split(GArg ga, GArg gb, GArg gc) {
  __shared__ __align__(16) short As[4096];   // [128 rows][32 k], XOR-swizzled 16B chunks
  __shared__ __align__(16) short Bs[4096];
  GArg A = (blockIdx.z == 0) ? ga : ((blockIdx.z == 1) ? gb : gc);
  const int t = threadIdx.x;
  const int w = t >> 6, lane = t & 63;
  const int col = lane & 15, quad = lane >> 4;
  const int m0 = blockIdx.x * 128, n0 = blockIdx.y * 128;
  const int wr = (w & 1) * 64, wc = (w >> 1) * 64;
  const int srow = lane >> 2, scs = lane & 3;
  floatx4 acc[4][4] = {};
  for (int kk = 0; kk < 3072; kk += 32) {
#pragma unroll
    for (int c = 0; c < 2; ++c) {
      int rowA = w * 32 + c * 16 + srow;
      int gch = scs ^ ((rowA >> 1) & 3);
      ASYNC16(A.X + (size_t)(m0 + rowA) * 3072 + kk + gch * 8, &As[(w * 32 + c * 16) * 32]);
      ASYNC16(A.W + (size_t)(n0 + rowA) * 3072 + kk + gch * 8, &Bs[(w * 32 + c * 16) * 32]);
    }
    __syncthreads();
    short8 af[4], bfr[4];
#pragma unroll
    for (int mt = 0; mt < 4; ++mt) {
      int row = wr + mt * 16 + col;
      af[mt] = *(const short8*)&As[row * 32 + ((quad ^ ((row >> 1) & 3)) & 3) * 8];
    }
#pragma unroll
    for (int nt = 0; nt < 4; ++nt) {
      int row = wc + nt * 16 + col;
      bfr[nt] = *(const short8*)&Bs[row * 32 + ((quad ^ ((row >> 1) & 3)) & 3) * 8];
    }
#pragma unroll
    for (int mt = 0; mt < 4; ++mt)
#pragma unroll
      for (int nt = 0; nt < 4; ++nt)
        acc[mt][nt] = MFMA16(af[mt], bfr[nt], acc[mt][nt]);
    __syncthreads();
  }
#pragma unroll
  for (int nt = 0; nt < 4; ++nt) {
    const int n = n0 + wc + nt * 16 + col;
    const float bias = A.bias[n];
#pragma unroll
    for (int mt = 0; mt < 4; ++mt)
#pragma unroll
      for (int r = 0; r < 4; ++r) {
        const int m = m0 + wr + mt * 16 + quad * 4 + r;
        float v = acc[mt][nt][r] + bias;
        if (A.mode == 0) {
          ((float*)A.o0)[(size_t)m * 1024 + n] = v;
        } else {
          short hi = f2bf(v), lo = f2bf(v - bf2f(hi));
          const int hh = n >> 6, d = n & 63;
          size_t off = (A.mode == 1) ? ((size_t)(hh * SEQ + m) * 64 + d)
                                     : ((size_t)(hh * 64 + d) * SEQ + m);
          ((short*)A.o0)[off] = hi;
          ((short*)A.o1)[off] = lo;
        }
      }
  }
}

// ---------------------------------------------------------------------------
// Flash CoPE attention, MFMA. One wave per block, 16 q-rows per wave.
// Key tiles processed last->first (reverse-cumsum carry). Split-bf16 QK & PV.
// QK:  D[key][qrow]  (A=K, B=Q)    PV: D[qrow][d] (A=P, B=V^T-stored)
// ---------------------------------------------------------------------------
__global__ __launch_bounds__(64)
void cope_attn_mfma(const short* __restrict__ Qhi, const short* __restrict__ Qlo,
                    const short* __restrict__ Khi, const short* __restrict__ Klo,
                    const short* __restrict__ Vthi, const short* __restrict__ Vtlo,
                    const short* __restrict__ peT, short* __restrict__ AOs) {
  __shared__ __align__(16) short Phi[16][72];   // [qrow][key] bf16 hi
  __shared__ __align__(16) short Plo[16][72];
  __shared__ float lis[16][68];                 // logits_int [qrow][npos]
  const int lane = threadIdx.x;
  const int col = lane & 15, quad = lane >> 4;
  const int h = blockIdx.x & 15;           // head round-robins with XCD -> L2 locality
  const int q0 = (blockIdx.x >> 4) * 16;

  short8 qB[2][2];
#pragma unroll
  for (int ks = 0; ks < 2; ++ks) {
    qB[ks][0] = *(const short8*)(Qhi + (size_t)(h * SEQ + q0 + col) * 64 + ks * 32 + quad * 8);
    qB[ks][1] = *(const short8*)(Qlo + (size_t)(h * SEQ + q0 + col) * 64 + ks * 32 + quad * 8);
  }

  // logits_int = Q · pos_emb  -> D[qrow=quad*4+reg][npos=col+16nt]
  floatx4 li[4] = {};
#pragma unroll
  for (int nt = 0; nt < 4; ++nt)
#pragma unroll
    for (int ks = 0; ks < 2; ++ks) {
      short8 pb = *(const short8*)(peT + (nt * 16 + col) * 64 + ks * 32 + quad * 8);
      li[nt] = MFMA16(qB[ks][0], pb, li[nt]);
    }
#pragma unroll
  for (int nt = 0; nt < 4; ++nt)
#pragma unroll
    for (int r = 0; r < 4; ++r)
      lis[quad * 4 + r][nt * 16 + col] = li[nt][r];
  __syncthreads();

  float mrow = -1e30f, lrow = 0.f, carry = 0.f;
  floatx4 O[4] = {};

  for (int kt = (SEQ / 64) - 1; kt >= 0; --kt) {
    const int k0 = kt * 64;
    floatx4 S[4] = {};
#pragma unroll
    for (int ksub = 0; ksub < 4; ++ksub) {
      const size_t krow = (size_t)(h * SEQ + k0 + ksub * 16 + col) * 64;
#pragma unroll
      for (int ks = 0; ks < 2; ++ks) {
        short8 kh = *(const short8*)(Khi + krow + ks * 32 + quad * 8);
        short8 kl = *(const short8*)(Klo + krow + ks * 32 + quad * 8);
        S[ksub] = MFMA16(kh, qB[ks][0], S[ksub]);   // hi·hi
        S[ksub] = MFMA16(kl, qB[ks][0], S[ksub]);   // lo·hi
        S[ksub] = MFMA16(kh, qB[ks][1], S[ksub]);   // hi·lo
      }
    }
    float sv[4][4], g[4][4];
#pragma unroll
    for (int ksub = 0; ksub < 4; ++ksub)
#pragma unroll
      for (int r = 0; r < 4; ++r) {
        float s = S[ksub][r] * 0.125f;
        sv[ksub][r] = s;
        g[ksub][r] = 1.0f / (1.0f + __expf(-s));
      }
    // inclusive suffix-sum over keys (key = ksub*16 + quad*4 + r), all rows parallel
    float pos[4][4];
    float run = carry;
#pragma unroll
    for (int ksub = 3; ksub >= 0; --ksub) {
      float s3 = g[ksub][3];
      float s2 = s3 + g[ksub][2];
      float s1 = s2 + g[ksub][1];
      float s0 = s1 + g[ksub][0];
      float t1 = __shfl_down(s0, 16, 64); t1 = (quad < 3) ? t1 : 0.f;
      float t2 = __shfl_down(s0, 32, 64); t2 = (quad < 2) ? t2 : 0.f;
      float t3 = __shfl_down(s0, 48, 64); t3 = (quad < 1) ? t3 : 0.f;
      float Sq = t1 + t2 + t3;                 // sum over higher quads
      float T = __shfl(Sq + s0, col, 64);      // ksub total (from quad 0)
      pos[ksub][0] = run + Sq + s0;
      pos[ksub][1] = run + Sq + s1;
      pos[ksub][2] = run + Sq + s2;
      pos[ksub][3] = run + Sq + s3;
      run += T;
    }
    carry = run;
    // CoPE interpolation + logits
    float a[4][4], mt = -1e30f;
#pragma unroll
    for (int ksub = 0; ksub < 4; ++ksub)
#pragma unroll
      for (int r = 0; r < 4; ++r) {
        float p = fminf(pos[ksub][r], 63.0f);
        float pf = floorf(p);
        int fi = (int)pf;
        int ci = (int)ceilf(p);
        float wq = p - pf;
        float lf = lis[col][fi], lc = lis[col][ci];
        float av = sv[ksub][r] + lc * wq + lf * (1.0f - wq);
        a[ksub][r] = av;
        mt = fmaxf(mt, av);
      }
    mt = fmaxf(mt, __shfl_xor(mt, 16, 64));
    mt = fmaxf(mt, __shfl_xor(mt, 32, 64));
    const float nm = fmaxf(mrow, mt);
    const float sc = __expf(mrow - nm);
    mrow = nm;
    float ps = 0.f;
    float p4[4][4];
#pragma unroll
    for (int ksub = 0; ksub < 4; ++ksub)
#pragma unroll
      for (int r = 0; r < 4; ++r) {
        float p = __expf(a[ksub][r] - nm);
        p4[ksub][r] = p;
        ps += p;
      }
    ps += __shfl_xor(ps, 16, 64);
    ps += __shfl_xor(ps, 32, 64);
    lrow = lrow * sc + ps;
    // P: D-layout -> A-layout via LDS (qrow stays on lane&15; key redistributes)
    __syncthreads();   // prior iter's Phi/Plo reads complete
#pragma unroll
    for (int ksub = 0; ksub < 4; ++ksub)
#pragma unroll
      for (int rp = 0; rp < 2; ++rp) {
        float p0 = p4[ksub][2 * rp], p1 = p4[ksub][2 * rp + 1];
        short h0 = f2bf(p0), h1 = f2bf(p1);
        short l0 = f2bf(p0 - bf2f(h0)), l1 = f2bf(p1 - bf2f(h1));
        int kidx = ksub * 16 + quad * 4 + 2 * rp;
        *(int*)&Phi[col][kidx] = (unsigned short)h0 | ((unsigned)(unsigned short)h1 << 16);
        *(int*)&Plo[col][kidx] = (unsigned short)l0 | ((unsigned)(unsigned short)l1 << 16);
      }
    __syncthreads();
    // PV
    float scv[4];
#pragma unroll
    for (int r = 0; r < 4; ++r) scv[r] = __shfl(sc, quad * 4 + r, 64);
#pragma unroll
    for (int dt = 0; dt < 4; ++dt)
#pragma unroll
      for (int r = 0; r < 4; ++r) O[dt][r] *= scv[r];
#pragma unroll
    for (int ks = 0; ks < 2; ++ks) {
      short8 pah = *(const short8*)&Phi[col][ks * 32 + quad * 8];
      short8 pal = *(const short8*)&Plo[col][ks * 32 + quad * 8];
#pragma unroll
      for (int dt = 0; dt < 4; ++dt) {
        const size_t vrow = (size_t)(h * 64 + dt * 16 + col) * SEQ + k0 + ks * 32 + quad * 8;
        short8 vh = *(const short8*)(Vthi + vrow);
        short8 vl = *(const short8*)(Vtlo + vrow);
        O[dt] = MFMA16(pah, vh, O[dt]);
        O[dt] = MFMA16(pal, vh, O[dt]);
        O[dt] = MFMA16(pah, vl, O[dt]);
      }
    }
  }
  // epilogue: normalize and write AO in split [hi|lo|hi] (X-side) layout
  float inv[4];
#pragma unroll
  for (int r = 0; r < 4; ++r) inv[r] = 1.0f / __shfl(lrow, quad * 4 + r, 64);
#pragma unroll
  for (int dt = 0; dt < 4; ++dt)
#pragma unroll
    for (int r = 0; r < 4; ++r) {
      float val = O[dt][r] * inv[r];
      int q = q0 + quad * 4 + r;
      int cg = h * 64 + dt * 16 + col;
      short hi = f2bf(val), lo = f2bf(val - bf2f(hi));
      AOs[(size_t)q * 3072 + cg] = hi;
      AOs[(size_t)q * 3072 + 1024 + cg] = lo;
      AOs[(size_t)q * 3072 + 2048 + cg] = hi;
    }
}

// ---------------------------------------------------------------------------
// Round-1 proven fp32 fallback (used only if ws_size is too small)
// ---------------------------------------------------------------------------
template <int MODE>
__global__ __launch_bounds__(256)
void gemm_bt_f32(const float* __restrict__ X, const float* __restrict__ W,
                 const float* __restrict__ bias, float* __restrict__ C,
                 int M, int N, int K) {
  __shared__ __align__(16) float Xs[16][68];
  __shared__ __align__(16) float Ws[16][68];
  const int t = threadIdx.x;
  const int tx = t & 15, ty = t >> 4;
  const int m0 = blockIdx.x * 64, n0 = blockIdx.y * 64;
  const int r = t >> 2;
  const int c4 = (t & 3) << 2;
  const float* Xp = X + (size_t)(m0 + r) * K + c4;
  const float* Wp = W + (size_t)(n0 + r) * K + c4;
  float acc[4][4] = {};
  for (int k0 = 0; k0 < K; k0 += 16) {
    float4 xv = *(const float4*)(Xp + k0);
    float4 wv = *(const float4*)(Wp + k0);
    __syncthreads();
    Xs[c4 + 0][r] = xv.x; Xs[c4 + 1][r] = xv.y; Xs[c4 + 2][r] = xv.z; Xs[c4 + 3][r] = xv.w;
    Ws[c4 + 0][r] = wv.x; Ws[c4 + 1][r] = wv.y; Ws[c4 + 2][r] = wv.z; Ws[c4 + 3][r] = wv.w;
    __syncthreads();
#pragma unroll
    for (int k = 0; k < 16; ++k) {
      const float4 xr = *(const float4*)&Xs[k][ty << 2];
      const float4 wr = *(const float4*)&Ws[k][tx << 2];
      const float xa[4] = {xr.x, xr.y, xr.z, xr.w};
      const float wa[4] = {wr.x, wr.y, wr.z, wr.w};
#pragma unroll
      for (int i = 0; i < 4; ++i)
#pragma unroll
        for (int j = 0; j < 4; ++j) acc[i][j] += xa[i] * wa[j];
    }
  }
#pragma unroll
  for (int i = 0; i < 4; ++i) {
    const int m = m0 + (ty << 2) + i;
#pragma unroll
    for (int j = 0; j < 4; ++j) {
      const int n = n0 + (tx << 2) + j;
      const float v = acc[i][j] + bias[n];
      if (MODE == 0) C[(size_t)m * N + n] = v;
      else { const int hh = n >> 6, d = n & 63; C[((size_t)hh * SEQ + m) * HD + d] = v; }
    }
  }
}

__global__ __launch_bounds__(256)
void cope_attn_f32(const float* __restrict__ Qh, const float* __restrict__ Kh,
                   const float* __restrict__ Vh, const float* __restrict__ pe,
                   float* __restrict__ AO) {
  __shared__ float Kt[64][65];
  __shared__ float Vt[64][65];
  __shared__ float lis[16][64];
  const int t = threadIdx.x;
  const int lane = t & 63;
  const int w = t >> 6;
  const int h = blockIdx.y;
  const int qbase = blockIdx.x * 16 + w * 4;
  float qreg[4];
#pragma unroll
  for (int rr = 0; rr < 4; ++rr)
    qreg[rr] = Qh[((size_t)h * SEQ + qbase + rr) * HD + lane];
  float li[4] = {0.f, 0.f, 0.f, 0.f};
  for (int d = 0; d < 64; ++d) {
    const float pv = pe[d * NPOSN + lane];
#pragma unroll
    for (int rr = 0; rr < 4; ++rr) li[rr] += lane_bcast(qreg[rr], d) * pv;
  }
#pragma unroll
  for (int rr = 0; rr < 4; ++rr) lis[w * 4 + rr][lane] = li[rr];
  float mrow[4] = {-1e30f, -1e30f, -1e30f, -1e30f};
  float lrow[4] = {0.f, 0.f, 0.f, 0.f};
  float carry[4] = {0.f, 0.f, 0.f, 0.f};
  float acc[4] = {0.f, 0.f, 0.f, 0.f};
  for (int kt = (SEQ / 64) - 1; kt >= 0; --kt) {
    const int k0 = kt * 64;
    __syncthreads();
#pragma unroll
    for (int i = 0; i < 4; ++i) {
      const int lin = t + i * 256;
      const int row = lin >> 4, cc = (lin & 15) << 2;
      const float4 kv = *(const float4*)(Kh + ((size_t)h * SEQ + k0 + row) * HD + cc);
      Kt[row][cc + 0] = kv.x; Kt[row][cc + 1] = kv.y; Kt[row][cc + 2] = kv.z; Kt[row][cc + 3] = kv.w;
      const float4 vv = *(const float4*)(Vh + ((size_t)h * SEQ + k0 + row) * HD + cc);
      Vt[row][cc + 0] = vv.x; Vt[row][cc + 1] = vv.y; Vt[row][cc + 2] = vv.z; Vt[row][cc + 3] = vv.w;
    }
    __syncthreads();
    float svv[4] = {0.f, 0.f, 0.f, 0.f};
#pragma unroll
    for (int d = 0; d < 64; ++d) {
      const float kd = Kt[lane][d];
#pragma unroll
      for (int rr = 0; rr < 4; ++rr) svv[rr] += lane_bcast(qreg[rr], d) * kd;
    }
    float p4[4], scl[4];
#pragma unroll
    for (int rr = 0; rr < 4; ++rr) {
      const float s = svv[rr] * 0.125f;
      const float gg = 1.0f / (1.0f + __expf(-s));
      float gs = gg;
#pragma unroll
      for (int off = 1; off < 64; off <<= 1) {
        const float tt = __shfl_down(gs, off, 64);
        gs += (lane + off < 64) ? tt : 0.0f;
      }
      const float tot = lane_bcast(gs, 0);
      float p = carry[rr] + gs;
      carry[rr] += tot;
      p = fminf(p, 63.0f);
      const float pf = floorf(p);
      const float wq = p - pf;
      const int fi = (int)pf;
      const int ci = (int)ceilf(p);
      const float cope = lis[w * 4 + rr][ci] * wq + lis[w * 4 + rr][fi] * (1.0f - wq);
      const float av = s + cope;
      float mt = av;
#pragma unroll
      for (int off = 32; off > 0; off >>= 1) mt = fmaxf(mt, __shfl_xor(mt, off, 64));
      const float nm = fmaxf(mrow[rr], mt);
      const float sc = __expf(mrow[rr] - nm);
      const float p2 = __expf(av - nm);
      float psum = p2;
#pragma unroll
      for (int off = 32; off > 0; off >>= 1) psum += __shfl_xor(psum, off, 64);
      lrow[rr] = lrow[rr] * sc + psum;
      mrow[rr] = nm;
      p4[rr] = p2;
      scl[rr] = sc;
    }
#pragma unroll
    for (int rr = 0; rr < 4; ++rr) acc[rr] *= scl[rr];
#pragma unroll
    for (int j = 0; j < 64; ++j) {
      const float vj = Vt[j][lane];
#pragma unroll
      for (int rr = 0; rr < 4; ++rr) acc[rr] += lane_bcast(p4[rr], j) * vj;
    }
  }
#pragma unroll
  for (int rr = 0; rr < 4; ++rr)
    AO[(size_t)(qbase + rr) * ND + h * HD + lane] = acc[rr] / lrow[rr];
}

// ---------------------------------------------------------------------------
extern "C" void kernel_launch(void* const* d_in, const int* in_sizes, int n_in,
                              void* d_out, int out_size, void* d_ws, size_t ws_size,
                              hipStream_t stream) {
  (void)in_sizes; (void)n_in; (void)out_size;
  const float* q    = (const float*)d_in[0];
  const float* k    = (const float*)d_in[1];
  const float* v    = (const float*)d_in[2];
  const float* Wq_w = (const float*)d_in[3];
  const float* Wq_b = (const float*)d_in[4];
  const float* Wk_w = (const float*)d_in[5];
  const float* Wk_b = (const float*)d_in[6];
  const float* Wv_w = (const float*)d_in[7];
  const float* Wv_b = (const float*)d_in[8];
  const float* Wo_w = (const float*)d_in[9];
  const float* Wo_b = (const float*)d_in[10];
  const float* pe   = (const float*)d_in[11];
  float* out = (float*)d_out;
  char* ws = (char*)d_ws;

  const size_t XSB = (size_t)SEQ * 3072 * 2;   // 12,582,912
  const size_t WSB = (size_t)1024 * 3072 * 2;  //  6,291,456
  const size_t HB  = (size_t)SEQ * 1024 * 2;   //  4,194,304
  const size_t FULL = 3 * XSB + 4 * WSB + 6 * HB + 8192;
  const size_t MID  = XSB + WSB + 6 * HB + 8192;

  if (ws_size >= FULL) {
    short* XSq = (short*)ws;
    short* XSk = (short*)(ws + XSB);
    short* XSv = (short*)(ws + 2 * XSB);
    short* WSq = (short*)(ws + 3 * XSB);
    short* WSk = (short*)(ws + 3 * XSB + WSB);
    short* WSv = (short*)(ws + 3 * XSB + 2 * WSB);
    short* WSo = (short*)(ws + 3 * XSB + 3 * WSB);
    char*  hb  = ws + 3 * XSB + 4 * WSB;
    short* Qhi = (short*)hb;             short* Qlo = (short*)(hb + HB);
    short* Khi = (short*)(hb + 2 * HB);  short* Klo = (short*)(hb + 3 * HB);
    short* Vthi = (short*)(hb + 4 * HB); short* Vtlo = (short*)(hb + 5 * HB);
    short* peT = (short*)(hb + 6 * HB);
    short* AOs = XSq;  // reuse after projections

    pe_transpose<<<1, 256, 0, stream>>>(pe, peT);
    split3_convert<<<2048, 256, 0, stream>>>(q, XSq, 2048 * 256, 0);
    split3_convert<<<2048, 256, 0, stream>>>(k, XSk, 2048 * 256, 0);
    split3_convert<<<2048, 256, 0, stream>>>(v, XSv, 2048 * 256, 0);
    split3_convert<<<1024, 256, 0, stream>>>(Wq_w, WSq, 1024 * 256, 1);
    split3_convert<<<1024, 256, 0, stream>>>(Wk_w, WSk, 1024 * 256, 1);
    split3_convert<<<1024, 256, 0, stream>>>(Wv_w, WSv, 1024 * 256, 1);
    split3_convert<<<1024, 256, 0, stream>>>(Wo_w, WSo, 1024 * 256, 1);
    GArg aq{XSq, WSq, Wq_b, Qhi, Qlo, 1};
    GArg ak{XSk, WSk, Wk_b, Khi, Klo, 1};
    GArg av{XSv, WSv, Wv_b, Vthi, Vtlo, 2};
    gemm_split<<<dim3(16, 8, 3), 256, 0, stream>>>(aq, ak, av);
    cope_attn_mfma<<<2048, 64, 0, stream>>>(Qhi, Qlo, Khi, Klo, Vthi, Vtlo, peT, AOs);
    GArg ao{AOs, WSo, Wo_b, (void*)out, nullptr, 0};
    gemm_split<<<dim3(16, 8, 1), 256, 0, stream>>>(ao, ao, ao);
  } else if (ws_size >= MID) {
    short* XS = (short*)ws;
    short* WS = (short*)(ws + XSB);
    char*  hb = ws + XSB + WSB;
    short* Qhi = (short*)hb;             short* Qlo = (short*)(hb + HB);
    short* Khi = (short*)(hb + 2 * HB);  short* Klo = (short*)(hb + 3 * HB);
    short* Vthi = (short*)(hb + 4 * HB); short* Vtlo = (short*)(hb + 5 * HB);
    short* peT = (short*)(hb + 6 * HB);
    short* AOs = XS;

    pe_transpose<<<1, 256, 0, stream>>>(pe, peT);
    split3_convert<<<2048, 256, 0, stream>>>(q, XS, 2048 * 256, 0);
    split3_convert<<<1024, 256, 0, stream>>>(Wq_w, WS, 1024 * 256, 1);
    { GArg a{XS, WS, Wq_b, Qhi, Qlo, 1}; gemm_split<<<dim3(16, 8, 1), 256, 0, stream>>>(a, a, a); }
    split3_convert<<<2048, 256, 0, stream>>>(k, XS, 2048 * 256, 0);
    split3_convert<<<1024, 256, 0, stream>>>(Wk_w, WS, 1024 * 256, 1);
    { GArg a{XS, WS, Wk_b, Khi, Klo, 1}; gemm_split<<<dim3(16, 8, 1), 256, 0, stream>>>(a, a, a); }
    split3_convert<<<2048, 256, 0, stream>>>(v, XS, 2048 * 256, 0);
    split3_convert<<<1024, 256, 0, stream>>>(Wv_w, WS, 1024 * 256, 1);
    { GArg a{XS, WS, Wv_b, Vthi, Vtlo, 2}; gemm_split<<<dim3(16, 8, 1), 256, 0, stream>>>(a, a, a); }
    cope_attn_mfma<<<2048, 64, 0, stream>>>(Qhi, Qlo, Khi, Klo, Vthi, Vtlo, peT, AOs);
    split3_convert<<<1024, 256, 0, stream>>>(Wo_w, WS, 1024 * 256, 1);
    { GArg a{AOs, WS, Wo_b, (void*)out, nullptr, 0}; gemm_split<<<dim3(16, 8, 1), 256, 0, stream>>>(a, a, a); }
  } else {
    const size_t per = (size_t)NH * SEQ * HD;
    float* Qh = (float*)d_ws;
    float* Kh = Qh + per;
    float* Vh = Kh + per;
    float* AO = Vh + per;
    dim3 gblk(256), ggrd(SEQ / 64, ND / 64);
    gemm_bt_f32<1><<<ggrd, gblk, 0, stream>>>(q, Wq_w, Wq_b, Qh, SEQ, ND, ND);
    gemm_bt_f32<1><<<ggrd, gblk, 0, stream>>>(k, Wk_w, Wk_b, Kh, SEQ, ND, ND);
    gemm_bt_f32<1><<<ggrd, gblk, 0, stream>>>(v, Wv_w, Wv_b, Vh, SEQ, ND, ND);
    cope_attn_f32<<<dim3(SEQ / 16, NH), 256, 0, stream>>>(Qh, Kh, Vh, pe, AO);
    gemm_bt_f32<0><<<ggrd, gblk, 0, stream>>>(AO, Wo_w, Wo_b, out, SEQ, ND, ND);
  }
}

// Round 4
// 383.502 us; speedup vs baseline: 2.8203x; 1.3872x over previous
//
#include <hip/hip_runtime.h>
#include <hip/hip_bf16.h>
#include <math.h>

#define SEQ 2048
#define ND  1024
#define NH  16
#define HD  64
#define NPOSN 64

typedef short short8 __attribute__((ext_vector_type(8)));
typedef short short4v __attribute__((ext_vector_type(4)));
typedef float floatx4 __attribute__((ext_vector_type(4)));

#define MFMA16(A, B, C) __builtin_amdgcn_mfma_f32_16x16x32_bf16((A), (B), (C), 0, 0, 0)

#define ASYNC16(gp, lp)                                                                     \
  __builtin_amdgcn_global_load_lds((const __attribute__((address_space(1))) unsigned int*)(gp), \
                                   (__attribute__((address_space(3))) unsigned int*)(lp), 16, 0, 0)

__device__ __forceinline__ short f2bf(float x) {
  __hip_bfloat16 h = __float2bfloat16(x);
  return *reinterpret_cast<short*>(&h);
}
__device__ __forceinline__ float bf2f(short s) {
  __hip_bfloat16 h = *reinterpret_cast<__hip_bfloat16*>(&s);
  return __bfloat162float(h);
}
__device__ __forceinline__ float lane_bcast(float v, int l) {
  return __int_as_float(__builtin_amdgcn_readlane(__float_as_int(v), l));
}

// ---------------------------------------------------------------------------
// fp32 -> split bf16 rows of 3072.
// wmode 0 (X side): [hi | lo | hi];  wmode 1 (W side): [hi | hi | lo]
// ---------------------------------------------------------------------------
__device__ __forceinline__ void split3_body(const float* __restrict__ in,
                                            short* __restrict__ out, int wmode) {
  int r = blockIdx.x;
  int c = threadIdx.x << 2;
  float4 v = *(const float4*)(in + (size_t)r * 1024 + c);
  short4v hi, lo;
  hi.x = f2bf(v.x); lo.x = f2bf(v.x - bf2f(hi.x));
  hi.y = f2bf(v.y); lo.y = f2bf(v.y - bf2f(hi.y));
  hi.z = f2bf(v.z); lo.z = f2bf(v.z - bf2f(hi.z));
  hi.w = f2bf(v.w); lo.w = f2bf(v.w - bf2f(hi.w));
  *(short4v*)(out + (size_t)r * 3072 + c) = hi;
  if (wmode == 0) {
    *(short4v*)(out + (size_t)r * 3072 + 1024 + c) = lo;
    *(short4v*)(out + (size_t)r * 3072 + 2048 + c) = hi;
  } else {
    *(short4v*)(out + (size_t)r * 3072 + 1024 + c) = hi;
    *(short4v*)(out + (size_t)r * 3072 + 2048 + c) = lo;
  }
}

__global__ __launch_bounds__(256)
void split3_convert(const float* __restrict__ in, short* __restrict__ out,
                    int total4, int wmode) {
  (void)total4;
  split3_body(in, out, wmode);
}

__global__ __launch_bounds__(256)
void split3_batch3(const float* a0, short* b0, const float* a1, short* b1,
                   const float* a2, short* b2) {
  const float* in = (blockIdx.z == 0) ? a0 : (blockIdx.z == 1 ? a1 : a2);
  short* out = (blockIdx.z == 0) ? b0 : (blockIdx.z == 1 ? b1 : b2);
  split3_body(in, out, 0);
}

__global__ __launch_bounds__(256)
void split3_batch4(const float* a0, short* b0, const float* a1, short* b1,
                   const float* a2, short* b2, const float* a3, short* b3) {
  const float* in = (blockIdx.z == 0) ? a0 : (blockIdx.z == 1 ? a1 : (blockIdx.z == 2 ? a2 : a3));
  short* out = (blockIdx.z == 0) ? b0 : (blockIdx.z == 1 ? b1 : (blockIdx.z == 2 ? b2 : b3));
  split3_body(in, out, 1);
}

__global__ __launch_bounds__(256)
void pe_transpose(const float* __restrict__ pe, short* __restrict__ peT) {
  for (int i = threadIdx.x; i < 4096; i += 256) {
    int n = i >> 6, d = i & 63;
    peT[n * 64 + d] = f2bf(pe[d * 64 + n]);   // peT[npos][d]
  }
}

// ---------------------------------------------------------------------------
// Split-bf16 MFMA GEMM: C[M,N] = Xs[M,3072] · Ws[N,3072]^T + bias
// mode 0: fp32 out [M][1024]
// mode 1: head split bf16: o0/o1 = hi/lo at [h][m][64]
// mode 2: head transposed split: hi/lo at [h][64][m]
// ---------------------------------------------------------------------------
struct GArg {
  const short* X; const short* W; const float* bias;
  void* o0; void* o1; int mode;
};

__global__ __launch_bounds__(256)
void gemm_split(GArg ga, GArg gb, GArg gc) {
  __shared__ __align__(16) short As[4096];   // [128 rows][32 k], XOR-swizzled 16B chunks
  __shared__ __align__(16) short Bs[4096];
  GArg A = (blockIdx.z == 0) ? ga : ((blockIdx.z == 1) ? gb : gc);
  const int t = threadIdx.x;
  const int w = t >> 6, lane = t & 63;
  const int col = lane & 15, quad = lane >> 4;
  const int m0 = blockIdx.x * 128, n0 = blockIdx.y * 128;
  const int wr = (w & 1) * 64, wc = (w >> 1) * 64;
  const int srow = lane >> 2, scs = lane & 3;
  floatx4 acc[4][4] = {};
  for (int kk = 0; kk < 3072; kk += 32) {
#pragma unroll
    for (int c = 0; c < 2; ++c) {
      int rowA = w * 32 + c * 16 + srow;
      int gch = scs ^ ((rowA >> 1) & 3);
      ASYNC16(A.X + (size_t)(m0 + rowA) * 3072 + kk + gch * 8, &As[(w * 32 + c * 16) * 32]);
      ASYNC16(A.W + (size_t)(n0 + rowA) * 3072 + kk + gch * 8, &Bs[(w * 32 + c * 16) * 32]);
    }
    __syncthreads();
    short8 af[4], bfr[4];
#pragma unroll
    for (int mt = 0; mt < 4; ++mt) {
      int row = wr + mt * 16 + col;
      af[mt] = *(const short8*)&As[row * 32 + ((quad ^ ((row >> 1) & 3)) & 3) * 8];
    }
#pragma unroll
    for (int nt = 0; nt < 4; ++nt) {
      int row = wc + nt * 16 + col;
      bfr[nt] = *(const short8*)&Bs[row * 32 + ((quad ^ ((row >> 1) & 3)) & 3) * 8];
    }
#pragma unroll
    for (int mt = 0; mt < 4; ++mt)
#pragma unroll
      for (int nt = 0; nt < 4; ++nt)
        acc[mt][nt] = MFMA16(af[mt], bfr[nt], acc[mt][nt]);
    __syncthreads();
  }
#pragma unroll
  for (int nt = 0; nt < 4; ++nt) {
    const int n = n0 + wc + nt * 16 + col;
    const float bias = A.bias[n];
#pragma unroll
    for (int mt = 0; mt < 4; ++mt)
#pragma unroll
      for (int r = 0; r < 4; ++r) {
        const int m = m0 + wr + mt * 16 + quad * 4 + r;
        float v = acc[mt][nt][r] + bias;
        if (A.mode == 0) {
          ((float*)A.o0)[(size_t)m * 1024 + n] = v;
        } else {
          short hi = f2bf(v), lo = f2bf(v - bf2f(hi));
          const int hh = n >> 6, d = n & 63;
          size_t off = (A.mode == 1) ? ((size_t)(hh * SEQ + m) * 64 + d)
                                     : ((size_t)(hh * 64 + d) * SEQ + m);
          ((short*)A.o0)[off] = hi;
          ((short*)A.o1)[off] = lo;
        }
      }
  }
}

// ---------------------------------------------------------------------------
// Flash CoPE attention v2. 1 wave/block, 16 q-rows. Key tiles last->first.
// No-max softmax (logits bounded ~10), per-lane deferred lrow, 1-hop scan,
// no barriers, register-double-buffered K, V issued at tile top.
// QK: A=K_hi, B=Q_split -> D[key=quad*4+r][qrow=col]
// PV: A=P_hi (LDS transpose), B=V_hi^T -> D[qrow=quad*4+r][d=col+16dt]
// ---------------------------------------------------------------------------
__global__ __launch_bounds__(64, 2)
void cope_attn_mfma(const short* __restrict__ Qhi, const short* __restrict__ Qlo,
                    const short* __restrict__ Khi, const short* __restrict__ Vthi,
                    const short* __restrict__ peT, short* __restrict__ AOs) {
  __shared__ __align__(16) short Phi[16][72];
  __shared__ float lis[16][68];
  const int lane = threadIdx.x;
  const int col = lane & 15, quad = lane >> 4;
  const int h = blockIdx.x & 15;
  const int q0 = (blockIdx.x >> 4) * 16;

  const short* Kb = Khi + (size_t)h * SEQ * 64;
  const short* Vb = Vthi + (size_t)h * 64 * SEQ;

  short8 qB[2][2];
#pragma unroll
  for (int ks = 0; ks < 2; ++ks) {
    qB[ks][0] = *(const short8*)(Qhi + (size_t)(h * SEQ + q0 + col) * 64 + ks * 32 + quad * 8);
    qB[ks][1] = *(const short8*)(Qlo + (size_t)(h * SEQ + q0 + col) * 64 + ks * 32 + quad * 8);
  }

  // logits_int = Q · pos_emb (full split) -> D[qrow=quad*4+r][npos=col+16nt]
  {
    floatx4 li[4] = {};
#pragma unroll
    for (int nt = 0; nt < 4; ++nt)
#pragma unroll
      for (int ks = 0; ks < 2; ++ks) {
        short8 pb = *(const short8*)(peT + (nt * 16 + col) * 64 + ks * 32 + quad * 8);
        li[nt] = MFMA16(qB[ks][0], pb, li[nt]);
        li[nt] = MFMA16(qB[ks][1], pb, li[nt]);
      }
#pragma unroll
    for (int nt = 0; nt < 4; ++nt)
#pragma unroll
      for (int r = 0; r < 4; ++r)
        lis[quad * 4 + r][nt * 16 + col] = li[nt][r];
  }
  // no barrier: 1 wave/block, DS ops are wave-ordered

  float lrow = 0.f;
  float carry = 0.f;
  floatx4 O[4] = {};

  short8 kA[4][2], kB[4][2];
  auto loadK = [&](int kt, short8 (&kd)[4][2]) {
#pragma unroll
    for (int ksub = 0; ksub < 4; ++ksub)
#pragma unroll
      for (int ks = 0; ks < 2; ++ks)
        kd[ksub][ks] =
            *(const short8*)(Kb + (size_t)(kt * 64 + ksub * 16 + col) * 64 + ks * 32 + quad * 8);
  };

  auto body = [&](int kt, short8 (&K)[4][2]) {
    // V loads for this tile, issued early (consumed after the softmax chain)
    short8 vh[2][4];
#pragma unroll
    for (int ks = 0; ks < 2; ++ks)
#pragma unroll
      for (int dt = 0; dt < 4; ++dt)
        vh[ks][dt] =
            *(const short8*)(Vb + (size_t)(dt * 16 + col) * SEQ + kt * 64 + ks * 32 + quad * 8);
    // QK (K hi · Q split)
    floatx4 S[4] = {};
#pragma unroll
    for (int ksub = 0; ksub < 4; ++ksub)
#pragma unroll
      for (int ks = 0; ks < 2; ++ks) {
        S[ksub] = MFMA16(K[ksub][ks], qB[ks][0], S[ksub]);
        S[ksub] = MFMA16(K[ksub][ks], qB[ks][1], S[ksub]);
      }
    // gates
    float sv[4][4], g[4][4];
#pragma unroll
    for (int ksub = 0; ksub < 4; ++ksub)
#pragma unroll
      for (int r = 0; r < 4; ++r) {
        float s = S[ksub][r] * 0.125f;
        sv[ksub][r] = s;
        g[ksub][r] = __builtin_amdgcn_rcpf(1.0f + __expf(-s));
      }
    // suffix-scan: all shuffles independent -> single DS latency hop
    float l[4][4], S4[4];
#pragma unroll
    for (int ksub = 0; ksub < 4; ++ksub) {
      l[ksub][3] = g[ksub][3];
      l[ksub][2] = l[ksub][3] + g[ksub][2];
      l[ksub][1] = l[ksub][2] + g[ksub][1];
      l[ksub][0] = l[ksub][1] + g[ksub][0];
      S4[ksub] = l[ksub][0];
    }
    float Sq[4], T[4];
#pragma unroll
    for (int ksub = 0; ksub < 4; ++ksub) {
      float d16 = __shfl_down(S4[ksub], 16, 64);
      float d32 = __shfl_down(S4[ksub], 32, 64);
      float d48 = __shfl_down(S4[ksub], 48, 64);
      float u16 = __shfl_up(S4[ksub], 16, 64);
      float u32 = __shfl_up(S4[ksub], 32, 64);
      float u48 = __shfl_up(S4[ksub], 48, 64);
      float sq = ((quad < 3) ? d16 : 0.f) + ((quad < 2) ? d32 : 0.f) + ((quad < 1) ? d48 : 0.f);
      float pq = ((quad > 0) ? u16 : 0.f) + ((quad > 1) ? u32 : 0.f) + ((quad > 2) ? u48 : 0.f);
      Sq[ksub] = sq;
      T[ksub] = pq + S4[ksub] + sq;
    }
    float U[4];
    U[3] = carry;
    U[2] = U[3] + T[3];
    U[1] = U[2] + T[2];
    U[0] = U[1] + T[1];
    carry = U[0] + T[0];
    // CoPE interp + exp (no max subtraction), pack P to bf16
    float p4[4][4];
#pragma unroll
    for (int ksub = 0; ksub < 4; ++ksub)
#pragma unroll
      for (int r = 0; r < 4; ++r) {
        float p = fminf(U[ksub] + Sq[ksub] + l[ksub][r], 63.0f);
        float pf = floorf(p);
        int fi = (int)pf;
        int ci = (int)ceilf(p);
        float wq = p - pf;
        float lf = lis[col][fi], lc = lis[col][ci];
        float pr = __expf(sv[ksub][r] + lc * wq + lf * (1.0f - wq));
        p4[ksub][r] = pr;
        lrow += pr;
      }
    // P: D-layout -> A-layout through LDS (wave-ordered, no barrier)
#pragma unroll
    for (int ksub = 0; ksub < 4; ++ksub)
#pragma unroll
      for (int rp = 0; rp < 2; ++rp) {
        short h0 = f2bf(p4[ksub][2 * rp]);
        short h1 = f2bf(p4[ksub][2 * rp + 1]);
        *(int*)&Phi[col][ksub * 16 + quad * 4 + 2 * rp] =
            (unsigned short)h0 | ((unsigned)(unsigned short)h1 << 16);
      }
    short8 pa[2];
#pragma unroll
    for (int ks = 0; ks < 2; ++ks)
      pa[ks] = *(const short8*)&Phi[col][ks * 32 + quad * 8];
    // PV (bf16-only)
#pragma unroll
    for (int ks = 0; ks < 2; ++ks)
#pragma unroll
      for (int dt = 0; dt < 4; ++dt)
        O[dt] = MFMA16(pa[ks], vh[ks][dt], O[dt]);
  };

  loadK(31, kA);
#pragma unroll 1
  for (int it = 0; it < 16; ++it) {
    int kt = 31 - 2 * it;
    loadK(kt - 1, kB);
    body(kt, kA);
    loadK(kt - 2 >= 0 ? kt - 2 : 0, kA);
    body(kt - 1, kB);
  }

  // epilogue: reduce lrow (deferred), normalize, write split AO
  float lr = lrow;
  lr += __shfl_xor(lr, 16, 64);
  lr += __shfl_xor(lr, 32, 64);   // full row sum, replicated over quads (row = col)
  float inv[4];
#pragma unroll
  for (int r = 0; r < 4; ++r) inv[r] = 1.0f / __shfl(lr, quad * 4 + r, 64);
#pragma unroll
  for (int dt = 0; dt < 4; ++dt)
#pragma unroll
    for (int r = 0; r < 4; ++r) {
      float val = O[dt][r] * inv[r];
      int q = q0 + quad * 4 + r;
      int cg = h * 64 + dt * 16 + col;
      short hi = f2bf(val), lo = f2bf(val - bf2f(hi));
      AOs[(size_t)q * 3072 + cg] = hi;
      AOs[(size_t)q * 3072 + 1024 + cg] = lo;
      AOs[(size_t)q * 3072 + 2048 + cg] = hi;
    }
}

// ---------------------------------------------------------------------------
// Round-1 proven fp32 fallback (used only if ws_size is too small)
// ---------------------------------------------------------------------------
template <int MODE>
__global__ __launch_bounds__(256)
void gemm_bt_f32(const float* __restrict__ X, const float* __restrict__ W,
                 const float* __restrict__ bias, float* __restrict__ C,
                 int M, int N, int K) {
  __shared__ __align__(16) float Xs[16][68];
  __shared__ __align__(16) float Ws[16][68];
  const int t = threadIdx.x;
  const int tx = t & 15, ty = t >> 4;
  const int m0 = blockIdx.x * 64, n0 = blockIdx.y * 64;
  const int r = t >> 2;
  const int c4 = (t & 3) << 2;
  const float* Xp = X + (size_t)(m0 + r) * K + c4;
  const float* Wp = W + (size_t)(n0 + r) * K + c4;
  float acc[4][4] = {};
  for (int k0 = 0; k0 < K; k0 += 16) {
    float4 xv = *(const float4*)(Xp + k0);
    float4 wv = *(const float4*)(Wp + k0);
    __syncthreads();
    Xs[c4 + 0][r] = xv.x; Xs[c4 + 1][r] = xv.y; Xs[c4 + 2][r] = xv.z; Xs[c4 + 3][r] = xv.w;
    Ws[c4 + 0][r] = wv.x; Ws[c4 + 1][r] = wv.y; Ws[c4 + 2][r] = wv.z; Ws[c4 + 3][r] = wv.w;
    __syncthreads();
#pragma unroll
    for (int k = 0; k < 16; ++k) {
      const float4 xr = *(const float4*)&Xs[k][ty << 2];
      const float4 wr = *(const float4*)&Ws[k][tx << 2];
      const float xa[4] = {xr.x, xr.y, xr.z, xr.w};
      const float wa[4] = {wr.x, wr.y, wr.z, wr.w};
#pragma unroll
      for (int i = 0; i < 4; ++i)
#pragma unroll
        for (int j = 0; j < 4; ++j) acc[i][j] += xa[i] * wa[j];
    }
  }
#pragma unroll
  for (int i = 0; i < 4; ++i) {
    const int m = m0 + (ty << 2) + i;
#pragma unroll
    for (int j = 0; j < 4; ++j) {
      const int n = n0 + (tx << 2) + j;
      const float v = acc[i][j] + bias[n];
      if (MODE == 0) C[(size_t)m * N + n] = v;
      else { const int hh = n >> 6, d = n & 63; C[((size_t)hh * SEQ + m) * HD + d] = v; }
    }
  }
}

__global__ __launch_bounds__(256)
void cope_attn_f32(const float* __restrict__ Qh, const float* __restrict__ Kh,
                   const float* __restrict__ Vh, const float* __restrict__ pe,
                   float* __restrict__ AO) {
  __shared__ float Kt[64][65];
  __shared__ float Vt[64][65];
  __shared__ float lis[16][64];
  const int t = threadIdx.x;
  const int lane = t & 63;
  const int w = t >> 6;
  const int h = blockIdx.y;
  const int qbase = blockIdx.x * 16 + w * 4;
  float qreg[4];
#pragma unroll
  for (int rr = 0; rr < 4; ++rr)
    qreg[rr] = Qh[((size_t)h * SEQ + qbase + rr) * HD + lane];
  float li[4] = {0.f, 0.f, 0.f, 0.f};
  for (int d = 0; d < 64; ++d) {
    const float pv = pe[d * NPOSN + lane];
#pragma unroll
    for (int rr = 0; rr < 4; ++rr) li[rr] += lane_bcast(qreg[rr], d) * pv;
  }
#pragma unroll
  for (int rr = 0; rr < 4; ++rr) lis[w * 4 + rr][lane] = li[rr];
  float mrow[4] = {-1e30f, -1e30f, -1e30f, -1e30f};
  float lrow[4] = {0.f, 0.f, 0.f, 0.f};
  float carry[4] = {0.f, 0.f, 0.f, 0.f};
  float acc[4] = {0.f, 0.f, 0.f, 0.f};
  for (int kt = (SEQ / 64) - 1; kt >= 0; --kt) {
    const int k0 = kt * 64;
    __syncthreads();
#pragma unroll
    for (int i = 0; i < 4; ++i) {
      const int lin = t + i * 256;
      const int row = lin >> 4, cc = (lin & 15) << 2;
      const float4 kv = *(const float4*)(Kh + ((size_t)h * SEQ + k0 + row) * HD + cc);
      Kt[row][cc + 0] = kv.x; Kt[row][cc + 1] = kv.y; Kt[row][cc + 2] = kv.z; Kt[row][cc + 3] = kv.w;
      const float4 vv = *(const float4*)(Vh + ((size_t)h * SEQ + k0 + row) * HD + cc);
      Vt[row][cc + 0] = vv.x; Vt[row][cc + 1] = vv.y; Vt[row][cc + 2] = vv.z; Vt[row][cc + 3] = vv.w;
    }
    __syncthreads();
    float svv[4] = {0.f, 0.f, 0.f, 0.f};
#pragma unroll
    for (int d = 0; d < 64; ++d) {
      const float kd = Kt[lane][d];
#pragma unroll
      for (int rr = 0; rr < 4; ++rr) svv[rr] += lane_bcast(qreg[rr], d) * kd;
    }
    float p4[4], scl[4];
#pragma unroll
    for (int rr = 0; rr < 4; ++rr) {
      const float s = svv[rr] * 0.125f;
      const float gg = 1.0f / (1.0f + __expf(-s));
      float gs = gg;
#pragma unroll
      for (int off = 1; off < 64; off <<= 1) {
        const float tt = __shfl_down(gs, off, 64);
        gs += (lane + off < 64) ? tt : 0.0f;
      }
      const float tot = lane_bcast(gs, 0);
      float p = carry[rr] + gs;
      carry[rr] += tot;
      p = fminf(p, 63.0f);
      const float pf = floorf(p);
      const float wq = p - pf;
      const int fi = (int)pf;
      const int ci = (int)ceilf(p);
      const float cope = lis[w * 4 + rr][ci] * wq + lis[w * 4 + rr][fi] * (1.0f - wq);
      const float av = s + cope;
      float mt = av;
#pragma unroll
      for (int off = 32; off > 0; off >>= 1) mt = fmaxf(mt, __shfl_xor(mt, off, 64));
      const float nm = fmaxf(mrow[rr], mt);
      const float sc = __expf(mrow[rr] - nm);
      const float p2 = __expf(av - nm);
      float psum = p2;
#pragma unroll
      for (int off = 32; off > 0; off >>= 1) psum += __shfl_xor(psum, off, 64);
      lrow[rr] = lrow[rr] * sc + psum;
      mrow[rr] = nm;
      p4[rr] = p2;
      scl[rr] = sc;
    }
#pragma unroll
    for (int rr = 0; rr < 4; ++rr) acc[rr] *= scl[rr];
#pragma unroll
    for (int j = 0; j < 64; ++j) {
      const float vj = Vt[j][lane];
#pragma unroll
      for (int rr = 0; rr < 4; ++rr) acc[rr] += lane_bcast(p4[rr], j) * vj;
    }
  }
#pragma unroll
  for (int rr = 0; rr < 4; ++rr)
    AO[(size_t)(qbase + rr) * ND + h * HD + lane] = acc[rr] / lrow[rr];
}

// ---------------------------------------------------------------------------
extern "C" void kernel_launch(void* const* d_in, const int* in_sizes, int n_in,
                              void* d_out, int out_size, void* d_ws, size_t ws_size,
                              hipStream_t stream) {
  (void)in_sizes; (void)n_in; (void)out_size;
  const float* q    = (const float*)d_in[0];
  const float* k    = (const float*)d_in[1];
  const float* v    = (const float*)d_in[2];
  const float* Wq_w = (const float*)d_in[3];
  const float* Wq_b = (const float*)d_in[4];
  const float* Wk_w = (const float*)d_in[5];
  const float* Wk_b = (const float*)d_in[6];
  const float* Wv_w = (const float*)d_in[7];
  const float* Wv_b = (const float*)d_in[8];
  const float* Wo_w = (const float*)d_in[9];
  const float* Wo_b = (const float*)d_in[10];
  const float* pe   = (const float*)d_in[11];
  float* out = (float*)d_out;
  char* ws = (char*)d_ws;

  const size_t XSB = (size_t)SEQ * 3072 * 2;   // 12,582,912
  const size_t WSB = (size_t)1024 * 3072 * 2;  //  6,291,456
  const size_t HB  = (size_t)SEQ * 1024 * 2;   //  4,194,304
  const size_t FULL = 3 * XSB + 4 * WSB + 6 * HB + 8192;
  const size_t MID  = XSB + WSB + 6 * HB + 8192;

  if (ws_size >= FULL) {
    short* XSq = (short*)ws;
    short* XSk = (short*)(ws + XSB);
    short* XSv = (short*)(ws + 2 * XSB);
    short* WSq = (short*)(ws + 3 * XSB);
    short* WSk = (short*)(ws + 3 * XSB + WSB);
    short* WSv = (short*)(ws + 3 * XSB + 2 * WSB);
    short* WSo = (short*)(ws + 3 * XSB + 3 * WSB);
    char*  hb  = ws + 3 * XSB + 4 * WSB;
    short* Qhi = (short*)hb;             short* Qlo = (short*)(hb + HB);
    short* Khi = (short*)(hb + 2 * HB);  short* Klo = (short*)(hb + 3 * HB);
    short* Vthi = (short*)(hb + 4 * HB); short* Vtlo = (short*)(hb + 5 * HB);
    short* peT = (short*)(hb + 6 * HB);
    short* AOs = XSq;  // reuse after projections

    pe_transpose<<<1, 256, 0, stream>>>(pe, peT);
    split3_batch3<<<dim3(2048, 1, 3), 256, 0, stream>>>(q, XSq, k, XSk, v, XSv);
    split3_batch4<<<dim3(1024, 1, 4), 256, 0, stream>>>(Wq_w, WSq, Wk_w, WSk, Wv_w, WSv, Wo_w, WSo);
    GArg aq{XSq, WSq, Wq_b, Qhi, Qlo, 1};
    GArg ak{XSk, WSk, Wk_b, Khi, Klo, 1};
    GArg av{XSv, WSv, Wv_b, Vthi, Vtlo, 2};
    gemm_split<<<dim3(16, 8, 3), 256, 0, stream>>>(aq, ak, av);
    cope_attn_mfma<<<2048, 64, 0, stream>>>(Qhi, Qlo, Khi, Vthi, peT, AOs);
    GArg ao{AOs, WSo, Wo_b, (void*)out, nullptr, 0};
    gemm_split<<<dim3(16, 8, 1), 256, 0, stream>>>(ao, ao, ao);
  } else if (ws_size >= MID) {
    short* XS = (short*)ws;
    short* WS = (short*)(ws + XSB);
    char*  hb = ws + XSB + WSB;
    short* Qhi = (short*)hb;             short* Qlo = (short*)(hb + HB);
    short* Khi = (short*)(hb + 2 * HB);  short* Klo = (short*)(hb + 3 * HB);
    short* Vthi = (short*)(hb + 4 * HB); short* Vtlo = (short*)(hb + 5 * HB);
    short* peT = (short*)(hb + 6 * HB);
    short* AOs = XS;

    pe_transpose<<<1, 256, 0, stream>>>(pe, peT);
    split3_convert<<<2048, 256, 0, stream>>>(q, XS, 2048 * 256, 0);
    split3_convert<<<1024, 256, 0, stream>>>(Wq_w, WS, 1024 * 256, 1);
    { GArg a{XS, WS, Wq_b, Qhi, Qlo, 1}; gemm_split<<<dim3(16, 8, 1), 256, 0, stream>>>(a, a, a); }
    split3_convert<<<2048, 256, 0, stream>>>(k, XS, 2048 * 256, 0);
    split3_convert<<<1024, 256, 0, stream>>>(Wk_w, WS, 1024 * 256, 1);
    { GArg a{XS, WS, Wk_b, Khi, Klo, 1}; gemm_split<<<dim3(16, 8, 1), 256, 0, stream>>>(a, a, a); }
    split3_convert<<<2048, 256, 0, stream>>>(v, XS, 2048 * 256, 0);
    split3_convert<<<1024, 256, 0, stream>>>(Wv_w, WS, 1024 * 256, 1);
    { GArg a{XS, WS, Wv_b, Vthi, Vtlo, 2}; gemm_split<<<dim3(16, 8, 1), 256, 0, stream>>>(a, a, a); }
    cope_attn_mfma<<<2048, 64, 0, stream>>>(Qhi, Qlo, Khi, Vthi, peT, AOs);
    split3_convert<<<1024, 256, 0, stream>>>(Wo_w, WS, 1024 * 256, 1);
    { GArg a{AOs, WS, Wo_b, (void*)out, nullptr, 0}; gemm_split<<<dim3(16, 8, 1), 256, 0, stream>>>(a, a, a); }
  } else {
    const size_t per = (size_t)NH * SEQ * HD;
    float* Qh = (float*)d_ws;
    float* Kh = Qh + per;
    float* Vh = Kh + per;
    float* AO = Vh + per;
    dim3 gblk(256), ggrd(SEQ / 64, ND / 64);
    gemm_bt_f32<1><<<ggrd, gblk, 0, stream>>>(q, Wq_w, Wq_b, Qh, SEQ, ND, ND);
    gemm_bt_f32<1><<<ggrd, gblk, 0, stream>>>(k, Wk_w, Wk_b, Kh, SEQ, ND, ND);
    gemm_bt_f32<1><<<ggrd, gblk, 0, stream>>>(v, Wv_w, Wv_b, Vh, SEQ, ND, ND);
    cope_attn_f32<<<dim3(SEQ / 16, NH), 256, 0, stream>>>(Qh, Kh, Vh, pe, AO);
    gemm_bt_f32<0><<<ggrd, gblk, 0, stream>>>(AO, Wo_w, Wo_b, out, SEQ, ND, ND);
  }
}

// Round 5
// 325.726 us; speedup vs baseline: 3.3205x; 1.1774x over previous
//
#include <hip/hip_runtime.h>
#include <hip/hip_bf16.h>
#include <math.h>

#define SEQ 2048
#define ND  1024
#define NH  16
#define HD  64
#define NPOSN 64

typedef short short8 __attribute__((ext_vector_type(8)));
typedef short short4v __attribute__((ext_vector_type(4)));
typedef float floatx4 __attribute__((ext_vector_type(4)));

#define MFMA16(A, B, C) __builtin_amdgcn_mfma_f32_16x16x32_bf16((A), (B), (C), 0, 0, 0)

#define ASYNC16(gp, lp)                                                                     \
  __builtin_amdgcn_global_load_lds((const __attribute__((address_space(1))) unsigned int*)(gp), \
                                   (__attribute__((address_space(3))) unsigned int*)(lp), 16, 0, 0)

__device__ __forceinline__ short f2bf(float x) {
  __hip_bfloat16 h = __float2bfloat16(x);
  return *reinterpret_cast<short*>(&h);
}
__device__ __forceinline__ float bf2f(short s) {
  __hip_bfloat16 h = *reinterpret_cast<__hip_bfloat16*>(&s);
  return __bfloat162float(h);
}
__device__ __forceinline__ float lane_bcast(float v, int l) {
  return __int_as_float(__builtin_amdgcn_readlane(__float_as_int(v), l));
}

// ---------------------------------------------------------------------------
// fp32 -> split bf16 rows of 3072.
// wmode 0 (X side): [hi | lo | hi];  wmode 1 (W side): [hi | hi | lo]
// ---------------------------------------------------------------------------
__device__ __forceinline__ void split3_body(const float* __restrict__ in,
                                            short* __restrict__ out, int wmode) {
  int r = blockIdx.x;
  int c = threadIdx.x << 2;
  float4 v = *(const float4*)(in + (size_t)r * 1024 + c);
  short4v hi, lo;
  hi.x = f2bf(v.x); lo.x = f2bf(v.x - bf2f(hi.x));
  hi.y = f2bf(v.y); lo.y = f2bf(v.y - bf2f(hi.y));
  hi.z = f2bf(v.z); lo.z = f2bf(v.z - bf2f(hi.z));
  hi.w = f2bf(v.w); lo.w = f2bf(v.w - bf2f(hi.w));
  *(short4v*)(out + (size_t)r * 3072 + c) = hi;
  if (wmode == 0) {
    *(short4v*)(out + (size_t)r * 3072 + 1024 + c) = lo;
    *(short4v*)(out + (size_t)r * 3072 + 2048 + c) = hi;
  } else {
    *(short4v*)(out + (size_t)r * 3072 + 1024 + c) = hi;
    *(short4v*)(out + (size_t)r * 3072 + 2048 + c) = lo;
  }
}

__global__ __launch_bounds__(256)
void split3_convert(const float* __restrict__ in, short* __restrict__ out,
                    int total4, int wmode) {
  (void)total4;
  split3_body(in, out, wmode);
}

__global__ __launch_bounds__(256)
void split3_batch3(const float* a0, short* b0, const float* a1, short* b1,
                   const float* a2, short* b2) {
  const float* in = (blockIdx.z == 0) ? a0 : (blockIdx.z == 1 ? a1 : a2);
  short* out = (blockIdx.z == 0) ? b0 : (blockIdx.z == 1 ? b1 : b2);
  split3_body(in, out, 0);
}

__global__ __launch_bounds__(256)
void split3_batch4(const float* a0, short* b0, const float* a1, short* b1,
                   const float* a2, short* b2, const float* a3, short* b3) {
  const float* in = (blockIdx.z == 0) ? a0 : (blockIdx.z == 1 ? a1 : (blockIdx.z == 2 ? a2 : a3));
  short* out = (blockIdx.z == 0) ? b0 : (blockIdx.z == 1 ? b1 : (blockIdx.z == 2 ? b2 : b3));
  split3_body(in, out, 1);
}

__global__ __launch_bounds__(256)
void pe_transpose(const float* __restrict__ pe, short* __restrict__ peT) {
  for (int i = threadIdx.x; i < 4096; i += 256) {
    int n = i >> 6, d = i & 63;
    peT[n * 64 + d] = f2bf(pe[d * 64 + n]);   // peT[npos][d]
  }
}

// ---------------------------------------------------------------------------
// Split-bf16 MFMA GEMM: C[M,N] = Xs[M,3072] · Ws[N,3072]^T + bias
// mode 0: fp32 out [M][1024]
// mode 1: head split bf16: o0/o1 = hi/lo at [h][m][64]
// mode 2: head transposed split: hi/lo at [h][64][m]
// ---------------------------------------------------------------------------
struct GArg {
  const short* X; const short* W; const float* bias;
  void* o0; void* o1; int mode;
};

__global__ __launch_bounds__(256)
void gemm_split(GArg ga, GArg gb, GArg gc) {
  __shared__ __align__(16) short As[4096];   // [128 rows][32 k], XOR-swizzled 16B chunks
  __shared__ __align__(16) short Bs[4096];
  GArg A = (blockIdx.z == 0) ? ga : ((blockIdx.z == 1) ? gb : gc);
  const int t = threadIdx.x;
  const int w = t >> 6, lane = t & 63;
  const int col = lane & 15, quad = lane >> 4;
  const int m0 = blockIdx.x * 128, n0 = blockIdx.y * 128;
  const int wr = (w & 1) * 64, wc = (w >> 1) * 64;
  const int srow = lane >> 2, scs = lane & 3;
  floatx4 acc[4][4] = {};
  for (int kk = 0; kk < 3072; kk += 32) {
#pragma unroll
    for (int c = 0; c < 2; ++c) {
      int rowA = w * 32 + c * 16 + srow;
      int gch = scs ^ ((rowA >> 1) & 3);
      ASYNC16(A.X + (size_t)(m0 + rowA) * 3072 + kk + gch * 8, &As[(w * 32 + c * 16) * 32]);
      ASYNC16(A.W + (size_t)(n0 + rowA) * 3072 + kk + gch * 8, &Bs[(w * 32 + c * 16) * 32]);
    }
    __syncthreads();
    short8 af[4], bfr[4];
#pragma unroll
    for (int mt = 0; mt < 4; ++mt) {
      int row = wr + mt * 16 + col;
      af[mt] = *(const short8*)&As[row * 32 + ((quad ^ ((row >> 1) & 3)) & 3) * 8];
    }
#pragma unroll
    for (int nt = 0; nt < 4; ++nt) {
      int row = wc + nt * 16 + col;
      bfr[nt] = *(const short8*)&Bs[row * 32 + ((quad ^ ((row >> 1) & 3)) & 3) * 8];
    }
#pragma unroll
    for (int mt = 0; mt < 4; ++mt)
#pragma unroll
      for (int nt = 0; nt < 4; ++nt)
        acc[mt][nt] = MFMA16(af[mt], bfr[nt], acc[mt][nt]);
    __syncthreads();
  }
#pragma unroll
  for (int nt = 0; nt < 4; ++nt) {
    const int n = n0 + wc + nt * 16 + col;
    const float bias = A.bias[n];
#pragma unroll
    for (int mt = 0; mt < 4; ++mt)
#pragma unroll
      for (int r = 0; r < 4; ++r) {
        const int m = m0 + wr + mt * 16 + quad * 4 + r;
        float v = acc[mt][nt][r] + bias;
        if (A.mode == 0) {
          ((float*)A.o0)[(size_t)m * 1024 + n] = v;
        } else {
          short hi = f2bf(v), lo = f2bf(v - bf2f(hi));
          const int hh = n >> 6, d = n & 63;
          size_t off = (A.mode == 1) ? ((size_t)(hh * SEQ + m) * 64 + d)
                                     : ((size_t)(hh * 64 + d) * SEQ + m);
          ((short*)A.o0)[off] = hi;
          ((short*)A.o1)[off] = lo;
        }
      }
  }
}

// ---------------------------------------------------------------------------
// Flash CoPE attention v3. 256-thr blocks = 4 waves × 16 q-rows (64-q block).
// K/V tiles staged in LDS via global_load_lds DMA (double-buffered, XOR-
// swizzled 16B chunks), shared by all 4 waves. Key tiles last->first
// (reverse-cumsum carry). No-max softmax, per-lane deferred lrow, 1-hop scan.
// QK: A=K_hi, B=Q_split -> D[key=quad*4+r][qrow=col]
// PV: A=P_hi (LDS transpose), B=V_hi^T -> D[qrow=quad*4+r][d=col+16dt]
// ---------------------------------------------------------------------------
__global__ __launch_bounds__(256, 2)
void cope_attn_mfma(const short* __restrict__ Qhi, const short* __restrict__ Qlo,
                    const short* __restrict__ Khi, const short* __restrict__ Vthi,
                    const short* __restrict__ peT, short* __restrict__ AOs) {
  __shared__ __align__(16) short Klds[2][4096];   // [buf][row 0..63][chunk^swz]
  __shared__ __align__(16) short Vlds[2][4096];   // [buf][d 0..63][chunk^swz]
  __shared__ __align__(16) short Phi[4][16][72];  // per-wave P transpose
  __shared__ float2 lis2[4][16][65];              // per-wave (lis[p], lis[p+1])
  const int tid = threadIdx.x;
  const int w = tid >> 6, lane = tid & 63;
  const int col = lane & 15, quad = lane >> 4;
  const int h = blockIdx.x & 15;
  const int q0 = (blockIdx.x >> 4) * 64 + w * 16;

  const short* Kb = Khi + (size_t)h * SEQ * 64;
  const short* Vb = Vthi + (size_t)h * 64 * SEQ;

  const int lrow8 = lane >> 3;                 // 0..7
  const int src_c = (lane & 7) ^ lrow8;        // XOR-swizzled source chunk

  // staging: wave w issues DMA instrs {2w, 2w+1} for K and V (8 rows each)
  auto stage = [&](int kt, int buf) {
#pragma unroll
    for (int i = 0; i < 2; ++i) {
      const int inst = 2 * w + i;
      const int row = inst * 8 + lrow8;
      ASYNC16(Kb + (size_t)(kt * 64 + row) * 64 + src_c * 8, &Klds[buf][inst * 512]);
      ASYNC16(Vb + (size_t)row * SEQ + kt * 64 + src_c * 8, &Vlds[buf][inst * 512]);
    }
  };

  short8 qB[2][2];
#pragma unroll
  for (int ks = 0; ks < 2; ++ks) {
    qB[ks][0] = *(const short8*)(Qhi + (size_t)(h * SEQ + q0 + col) * 64 + ks * 32 + quad * 8);
    qB[ks][1] = *(const short8*)(Qlo + (size_t)(h * SEQ + q0 + col) * 64 + ks * 32 + quad * 8);
  }

  stage(31, 0);

  // logits_int = Q · pos_emb (full split) -> D[qrow=quad*4+r][npos=col+16nt]
  {
    floatx4 li[4] = {};
#pragma unroll
    for (int nt = 0; nt < 4; ++nt)
#pragma unroll
      for (int ks = 0; ks < 2; ++ks) {
        short8 pb = *(const short8*)(peT + (nt * 16 + col) * 64 + ks * 32 + quad * 8);
        li[nt] = MFMA16(qB[ks][0], pb, li[nt]);
        li[nt] = MFMA16(qB[ks][1], pb, li[nt]);
      }
#pragma unroll
    for (int nt = 0; nt < 4; ++nt)
#pragma unroll
      for (int r = 0; r < 4; ++r) {
        const int qr = quad * 4 + r;
        const int pos = nt * 16 + col;
        const float v = li[nt][r];
        lis2[w][qr][pos].x = v;
        if (pos > 0) lis2[w][qr][pos - 1].y = v;
        if (pos == 63) lis2[w][qr][63].y = v;
      }
  }
  __syncthreads();   // staging(31) drained + lis2 ready

  float lrow = 0.f;
  float carry = 0.f;
  floatx4 O[4] = {};

  const int swz = col & 7;

#pragma unroll 1
  for (int it = 0; it < 32; ++it) {
    const int kt = 31 - it;
    const int buf = it & 1;
    if (kt > 0) stage(kt - 1, buf ^ 1);

    // fragments from LDS (swizzled: chunk c stored at position c ^ (row&7))
    short8 kf[4][2], vf[2][4];
#pragma unroll
    for (int ksub = 0; ksub < 4; ++ksub)
#pragma unroll
      for (int ks = 0; ks < 2; ++ks)
        kf[ksub][ks] =
            *(const short8*)&Klds[buf][(ksub * 16 + col) * 64 + (((ks * 4 + quad) ^ swz) * 8)];
#pragma unroll
    for (int ks = 0; ks < 2; ++ks)
#pragma unroll
      for (int dt = 0; dt < 4; ++dt)
        vf[ks][dt] =
            *(const short8*)&Vlds[buf][(dt * 16 + col) * 64 + (((ks * 4 + quad) ^ swz) * 8)];

    // QK (K hi · Q split)
    floatx4 S[4] = {};
#pragma unroll
    for (int ksub = 0; ksub < 4; ++ksub)
#pragma unroll
      for (int ks = 0; ks < 2; ++ks) {
        S[ksub] = MFMA16(kf[ksub][ks], qB[ks][0], S[ksub]);
        S[ksub] = MFMA16(kf[ksub][ks], qB[ks][1], S[ksub]);
      }
    // gates
    float sv[4][4], g[4][4];
#pragma unroll
    for (int ksub = 0; ksub < 4; ++ksub)
#pragma unroll
      for (int r = 0; r < 4; ++r) {
        float s = S[ksub][r] * 0.125f;
        sv[ksub][r] = s;
        g[ksub][r] = __builtin_amdgcn_rcpf(1.0f + __expf(-s));
      }
    // suffix-scan: all shuffles independent -> single DS latency hop
    float l[4][4], S4[4];
#pragma unroll
    for (int ksub = 0; ksub < 4; ++ksub) {
      l[ksub][3] = g[ksub][3];
      l[ksub][2] = l[ksub][3] + g[ksub][2];
      l[ksub][1] = l[ksub][2] + g[ksub][1];
      l[ksub][0] = l[ksub][1] + g[ksub][0];
      S4[ksub] = l[ksub][0];
    }
    float Sq[4], T[4];
#pragma unroll
    for (int ksub = 0; ksub < 4; ++ksub) {
      float d16 = __shfl_down(S4[ksub], 16, 64);
      float d32 = __shfl_down(S4[ksub], 32, 64);
      float d48 = __shfl_down(S4[ksub], 48, 64);
      float u16 = __shfl_up(S4[ksub], 16, 64);
      float u32 = __shfl_up(S4[ksub], 32, 64);
      float u48 = __shfl_up(S4[ksub], 48, 64);
      float sq = ((quad < 3) ? d16 : 0.f) + ((quad < 2) ? d32 : 0.f) + ((quad < 1) ? d48 : 0.f);
      float pq = ((quad > 0) ? u16 : 0.f) + ((quad > 1) ? u32 : 0.f) + ((quad > 2) ? u48 : 0.f);
      Sq[ksub] = sq;
      T[ksub] = pq + S4[ksub] + sq;
    }
    float U[4];
    U[3] = carry;
    U[2] = U[3] + T[3];
    U[1] = U[2] + T[2];
    U[0] = U[1] + T[1];
    carry = U[0] + T[0];
    // CoPE interp + exp (no max subtraction)
    float p4[4][4];
#pragma unroll
    for (int ksub = 0; ksub < 4; ++ksub)
#pragma unroll
      for (int r = 0; r < 4; ++r) {
        float p = fminf(U[ksub] + Sq[ksub] + l[ksub][r], 63.0f);
        float pf = floorf(p);
        int fi = (int)pf;
        float wq = p - pf;
        float2 lfc = lis2[w][col][fi];
        float pr = __expf(sv[ksub][r] + lfc.x + wq * (lfc.y - lfc.x));
        p4[ksub][r] = pr;
        lrow += pr;
      }
    // P: D-layout -> A-layout through LDS (per-wave buffer, wave-ordered)
#pragma unroll
    for (int ksub = 0; ksub < 4; ++ksub)
#pragma unroll
      for (int rp = 0; rp < 2; ++rp) {
        short h0 = f2bf(p4[ksub][2 * rp]);
        short h1 = f2bf(p4[ksub][2 * rp + 1]);
        *(int*)&Phi[w][col][ksub * 16 + quad * 4 + 2 * rp] =
            (unsigned short)h0 | ((unsigned)(unsigned short)h1 << 16);
      }
    short8 pa[2];
#pragma unroll
    for (int ks = 0; ks < 2; ++ks)
      pa[ks] = *(const short8*)&Phi[w][col][ks * 32 + quad * 8];
    // PV (bf16-only)
#pragma unroll
    for (int ks = 0; ks < 2; ++ks)
#pragma unroll
      for (int dt = 0; dt < 4; ++dt)
        O[dt] = MFMA16(pa[ks], vf[ks][dt], O[dt]);

    __syncthreads();   // all waves done with buf; stage(kt-1) drained here
  }

  // epilogue: reduce lrow (deferred), normalize, write split AO
  float lr = lrow;
  lr += __shfl_xor(lr, 16, 64);
  lr += __shfl_xor(lr, 32, 64);   // full row sum, replicated over quads (row = col)
  float inv[4];
#pragma unroll
  for (int r = 0; r < 4; ++r) inv[r] = 1.0f / __shfl(lr, quad * 4 + r, 64);
#pragma unroll
  for (int dt = 0; dt < 4; ++dt)
#pragma unroll
    for (int r = 0; r < 4; ++r) {
      float val = O[dt][r] * inv[r];
      int q = q0 + quad * 4 + r;
      int cg = h * 64 + dt * 16 + col;
      short hi = f2bf(val), lo = f2bf(val - bf2f(hi));
      AOs[(size_t)q * 3072 + cg] = hi;
      AOs[(size_t)q * 3072 + 1024 + cg] = lo;
      AOs[(size_t)q * 3072 + 2048 + cg] = hi;
    }
}

// ---------------------------------------------------------------------------
// Round-1 proven fp32 fallback (used only if ws_size is too small)
// ---------------------------------------------------------------------------
template <int MODE>
__global__ __launch_bounds__(256)
void gemm_bt_f32(const float* __restrict__ X, const float* __restrict__ W,
                 const float* __restrict__ bias, float* __restrict__ C,
                 int M, int N, int K) {
  __shared__ __align__(16) float Xs[16][68];
  __shared__ __align__(16) float Ws[16][68];
  const int t = threadIdx.x;
  const int tx = t & 15, ty = t >> 4;
  const int m0 = blockIdx.x * 64, n0 = blockIdx.y * 64;
  const int r = t >> 2;
  const int c4 = (t & 3) << 2;
  const float* Xp = X + (size_t)(m0 + r) * K + c4;
  const float* Wp = W + (size_t)(n0 + r) * K + c4;
  float acc[4][4] = {};
  for (int k0 = 0; k0 < K; k0 += 16) {
    float4 xv = *(const float4*)(Xp + k0);
    float4 wv = *(const float4*)(Wp + k0);
    __syncthreads();
    Xs[c4 + 0][r] = xv.x; Xs[c4 + 1][r] = xv.y; Xs[c4 + 2][r] = xv.z; Xs[c4 + 3][r] = xv.w;
    Ws[c4 + 0][r] = wv.x; Ws[c4 + 1][r] = wv.y; Ws[c4 + 2][r] = wv.z; Ws[c4 + 3][r] = wv.w;
    __syncthreads();
#pragma unroll
    for (int k = 0; k < 16; ++k) {
      const float4 xr = *(const float4*)&Xs[k][ty << 2];
      const float4 wr = *(const float4*)&Ws[k][tx << 2];
      const float xa[4] = {xr.x, xr.y, xr.z, xr.w};
      const float wa[4] = {wr.x, wr.y, wr.z, wr.w};
#pragma unroll
      for (int i = 0; i < 4; ++i)
#pragma unroll
        for (int j = 0; j < 4; ++j) acc[i][j] += xa[i] * wa[j];
    }
  }
#pragma unroll
  for (int i = 0; i < 4; ++i) {
    const int m = m0 + (ty << 2) + i;
#pragma unroll
    for (int j = 0; j < 4; ++j) {
      const int n = n0 + (tx << 2) + j;
      const float v = acc[i][j] + bias[n];
      if (MODE == 0) C[(size_t)m * N + n] = v;
      else { const int hh = n >> 6, d = n & 63; C[((size_t)hh * SEQ + m) * HD + d] = v; }
    }
  }
}

__global__ __launch_bounds__(256)
void cope_attn_f32(const float* __restrict__ Qh, const float* __restrict__ Kh,
                   const float* __restrict__ Vh, const float* __restrict__ pe,
                   float* __restrict__ AO) {
  __shared__ float Kt[64][65];
  __shared__ float Vt[64][65];
  __shared__ float lis[16][64];
  const int t = threadIdx.x;
  const int lane = t & 63;
  const int w = t >> 6;
  const int h = blockIdx.y;
  const int qbase = blockIdx.x * 16 + w * 4;
  float qreg[4];
#pragma unroll
  for (int rr = 0; rr < 4; ++rr)
    qreg[rr] = Qh[((size_t)h * SEQ + qbase + rr) * HD + lane];
  float li[4] = {0.f, 0.f, 0.f, 0.f};
  for (int d = 0; d < 64; ++d) {
    const float pv = pe[d * NPOSN + lane];
#pragma unroll
    for (int rr = 0; rr < 4; ++rr) li[rr] += lane_bcast(qreg[rr], d) * pv;
  }
#pragma unroll
  for (int rr = 0; rr < 4; ++rr) lis[w * 4 + rr][lane] = li[rr];
  float mrow[4] = {-1e30f, -1e30f, -1e30f, -1e30f};
  float lrow[4] = {0.f, 0.f, 0.f, 0.f};
  float carry[4] = {0.f, 0.f, 0.f, 0.f};
  float acc[4] = {0.f, 0.f, 0.f, 0.f};
  for (int kt = (SEQ / 64) - 1; kt >= 0; --kt) {
    const int k0 = kt * 64;
    __syncthreads();
#pragma unroll
    for (int i = 0; i < 4; ++i) {
      const int lin = t + i * 256;
      const int row = lin >> 4, cc = (lin & 15) << 2;
      const float4 kv = *(const float4*)(Kh + ((size_t)h * SEQ + k0 + row) * HD + cc);
      Kt[row][cc + 0] = kv.x; Kt[row][cc + 1] = kv.y; Kt[row][cc + 2] = kv.z; Kt[row][cc + 3] = kv.w;
      const float4 vv = *(const float4*)(Vh + ((size_t)h * SEQ + k0 + row) * HD + cc);
      Vt[row][cc + 0] = vv.x; Vt[row][cc + 1] = vv.y; Vt[row][cc + 2] = vv.z; Vt[row][cc + 3] = vv.w;
    }
    __syncthreads();
    float svv[4] = {0.f, 0.f, 0.f, 0.f};
#pragma unroll
    for (int d = 0; d < 64; ++d) {
      const float kd = Kt[lane][d];
#pragma unroll
      for (int rr = 0; rr < 4; ++rr) svv[rr] += lane_bcast(qreg[rr], d) * kd;
    }
    float p4[4], scl[4];
#pragma unroll
    for (int rr = 0; rr < 4; ++rr) {
      const float s = svv[rr] * 0.125f;
      const float gg = 1.0f / (1.0f + __expf(-s));
      float gs = gg;
#pragma unroll
      for (int off = 1; off < 64; off <<= 1) {
        const float tt = __shfl_down(gs, off, 64);
        gs += (lane + off < 64) ? tt : 0.0f;
      }
      const float tot = lane_bcast(gs, 0);
      float p = carry[rr] + gs;
      carry[rr] += tot;
      p = fminf(p, 63.0f);
      const float pf = floorf(p);
      const float wq = p - pf;
      const int fi = (int)pf;
      const int ci = (int)ceilf(p);
      const float cope = lis[w * 4 + rr][ci] * wq + lis[w * 4 + rr][fi] * (1.0f - wq);
      const float av = s + cope;
      float mt = av;
#pragma unroll
      for (int off = 32; off > 0; off >>= 1) mt = fmaxf(mt, __shfl_xor(mt, off, 64));
      const float nm = fmaxf(mrow[rr], mt);
      const float sc = __expf(mrow[rr] - nm);
      const float p2 = __expf(av - nm);
      float psum = p2;
#pragma unroll
      for (int off = 32; off > 0; off >>= 1) psum += __shfl_xor(psum, off, 64);
      lrow[rr] = lrow[rr] * sc + psum;
      mrow[rr] = nm;
      p4[rr] = p2;
      scl[rr] = sc;
    }
#pragma unroll
    for (int rr = 0; rr < 4; ++rr) acc[rr] *= scl[rr];
#pragma unroll
    for (int j = 0; j < 64; ++j) {
      const float vj = Vt[j][lane];
#pragma unroll
      for (int rr = 0; rr < 4; ++rr) acc[rr] += lane_bcast(p4[rr], j) * vj;
    }
  }
#pragma unroll
  for (int rr = 0; rr < 4; ++rr)
    AO[(size_t)(qbase + rr) * ND + h * HD + lane] = acc[rr] / lrow[rr];
}

// ---------------------------------------------------------------------------
extern "C" void kernel_launch(void* const* d_in, const int* in_sizes, int n_in,
                              void* d_out, int out_size, void* d_ws, size_t ws_size,
                              hipStream_t stream) {
  (void)in_sizes; (void)n_in; (void)out_size;
  const float* q    = (const float*)d_in[0];
  const float* k    = (const float*)d_in[1];
  const float* v    = (const float*)d_in[2];
  const float* Wq_w = (const float*)d_in[3];
  const float* Wq_b = (const float*)d_in[4];
  const float* Wk_w = (const float*)d_in[5];
  const float* Wk_b = (const float*)d_in[6];
  const float* Wv_w = (const float*)d_in[7];
  const float* Wv_b = (const float*)d_in[8];
  const float* Wo_w = (const float*)d_in[9];
  const float* Wo_b = (const float*)d_in[10];
  const float* pe   = (const float*)d_in[11];
  float* out = (float*)d_out;
  char* ws = (char*)d_ws;

  const size_t XSB = (size_t)SEQ * 3072 * 2;   // 12,582,912
  const size_t WSB = (size_t)1024 * 3072 * 2;  //  6,291,456
  const size_t HB  = (size_t)SEQ * 1024 * 2;   //  4,194,304
  const size_t FULL = 3 * XSB + 4 * WSB + 6 * HB + 8192;
  const size_t MID  = XSB + WSB + 6 * HB + 8192;

  if (ws_size >= FULL) {
    short* XSq = (short*)ws;
    short* XSk = (short*)(ws + XSB);
    short* XSv = (short*)(ws + 2 * XSB);
    short* WSq = (short*)(ws + 3 * XSB);
    short* WSk = (short*)(ws + 3 * XSB + WSB);
    short* WSv = (short*)(ws + 3 * XSB + 2 * WSB);
    short* WSo = (short*)(ws + 3 * XSB + 3 * WSB);
    char*  hb  = ws + 3 * XSB + 4 * WSB;
    short* Qhi = (short*)hb;             short* Qlo = (short*)(hb + HB);
    short* Khi = (short*)(hb + 2 * HB);  short* Klo = (short*)(hb + 3 * HB);
    short* Vthi = (short*)(hb + 4 * HB); short* Vtlo = (short*)(hb + 5 * HB);
    short* peT = (short*)(hb + 6 * HB);
    short* AOs = XSq;  // reuse after projections

    pe_transpose<<<1, 256, 0, stream>>>(pe, peT);
    split3_batch3<<<dim3(2048, 1, 3), 256, 0, stream>>>(q, XSq, k, XSk, v, XSv);
    split3_batch4<<<dim3(1024, 1, 4), 256, 0, stream>>>(Wq_w, WSq, Wk_w, WSk, Wv_w, WSv, Wo_w, WSo);
    GArg aq{XSq, WSq, Wq_b, Qhi, Qlo, 1};
    GArg ak{XSk, WSk, Wk_b, Khi, Klo, 1};
    GArg av{XSv, WSv, Wv_b, Vthi, Vtlo, 2};
    gemm_split<<<dim3(16, 8, 3), 256, 0, stream>>>(aq, ak, av);
    cope_attn_mfma<<<512, 256, 0, stream>>>(Qhi, Qlo, Khi, Vthi, peT, AOs);
    GArg ao{AOs, WSo, Wo_b, (void*)out, nullptr, 0};
    gemm_split<<<dim3(16, 8, 1), 256, 0, stream>>>(ao, ao, ao);
  } else if (ws_size >= MID) {
    short* XS = (short*)ws;
    short* WS = (short*)(ws + XSB);
    char*  hb = ws + XSB + WSB;
    short* Qhi = (short*)hb;             short* Qlo = (short*)(hb + HB);
    short* Khi = (short*)(hb + 2 * HB);  short* Klo = (short*)(hb + 3 * HB);
    short* Vthi = (short*)(hb + 4 * HB); short* Vtlo = (short*)(hb + 5 * HB);
    short* peT = (short*)(hb + 6 * HB);
    short* AOs = XS;

    pe_transpose<<<1, 256, 0, stream>>>(pe, peT);
    split3_convert<<<2048, 256, 0, stream>>>(q, XS, 2048 * 256, 0);
    split3_convert<<<1024, 256, 0, stream>>>(Wq_w, WS, 1024 * 256, 1);
    { GArg a{XS, WS, Wq_b, Qhi, Qlo, 1}; gemm_split<<<dim3(16, 8, 1), 256, 0, stream>>>(a, a, a); }
    split3_convert<<<2048, 256, 0, stream>>>(k, XS, 2048 * 256, 0);
    split3_convert<<<1024, 256, 0, stream>>>(Wk_w, WS, 1024 * 256, 1);
    { GArg a{XS, WS, Wk_b, Khi, Klo, 1}; gemm_split<<<dim3(16, 8, 1), 256, 0, stream>>>(a, a, a); }
    split3_convert<<<2048, 256, 0, stream>>>(v, XS, 2048 * 256, 0);
    split3_convert<<<1024, 256, 0, stream>>>(Wv_w, WS, 1024 * 256, 1);
    { GArg a{XS, WS, Wv_b, Vthi, Vtlo, 2}; gemm_split<<<dim3(16, 8, 1), 256, 0, stream>>>(a, a, a); }
    cope_attn_mfma<<<512, 256, 0, stream>>>(Qhi, Qlo, Khi, Vthi, peT, AOs);
    split3_convert<<<1024, 256, 0, stream>>>(Wo_w, WS, 1024 * 256, 1);
    { GArg a{AOs, WS, Wo_b, (void*)out, nullptr, 0}; gemm_split<<<dim3(16, 8, 1), 256, 0, stream>>>(a, a, a); }
  } else {
    const size_t per = (size_t)NH * SEQ * HD;
    float* Qh = (float*)d_ws;
    float* Kh = Qh + per;
    float* Vh = Kh + per;
    float* AO = Vh + per;
    dim3 gblk(256), ggrd(SEQ / 64, ND / 64);
    gemm_bt_f32<1><<<ggrd, gblk, 0, stream>>>(q, Wq_w, Wq_b, Qh, SEQ, ND, ND);
    gemm_bt_f32<1><<<ggrd, gblk, 0, stream>>>(k, Wk_w, Wk_b, Kh, SEQ, ND, ND);
    gemm_bt_f32<1><<<ggrd, gblk, 0, stream>>>(v, Wv_w, Wv_b, Vh, SEQ, ND, ND);
    cope_attn_f32<<<dim3(SEQ / 16, NH), 256, 0, stream>>>(Qh, Kh, Vh, pe, AO);
    gemm_bt_f32<0><<<ggrd, gblk, 0, stream>>>(AO, Wo_w, Wo_b, out, SEQ, ND, ND);
  }
}

// Round 6
// 272.425 us; speedup vs baseline: 3.9702x; 1.1957x over previous
//
#include <hip/hip_runtime.h>
#include <hip/hip_bf16.h>
#include <math.h>

#define SEQ 2048
#define ND  1024
#define NH  16
#define HD  64
#define NPOSN 64

typedef short short8 __attribute__((ext_vector_type(8)));
typedef short short4v __attribute__((ext_vector_type(4)));
typedef float floatx4 __attribute__((ext_vector_type(4)));

#define MFMA16(A, B, C) __builtin_amdgcn_mfma_f32_16x16x32_bf16((A), (B), (C), 0, 0, 0)

#define ASYNC16(gp, lp)                                                                     \
  __builtin_amdgcn_global_load_lds((const __attribute__((address_space(1))) unsigned int*)(gp), \
                                   (__attribute__((address_space(3))) unsigned int*)(lp), 16, 0, 0)

__device__ __forceinline__ short f2bf(float x) {
  __hip_bfloat16 h = __float2bfloat16(x);
  return *reinterpret_cast<short*>(&h);
}
__device__ __forceinline__ float bf2f(short s) {
  __hip_bfloat16 h = *reinterpret_cast<__hip_bfloat16*>(&s);
  return __bfloat162float(h);
}
__device__ __forceinline__ float lane_bcast(float v, int l) {
  return __int_as_float(__builtin_amdgcn_readlane(__float_as_int(v), l));
}

// ---------------------------------------------------------------------------
// fp32 -> split bf16 rows of 3072.
// wmode 0 (X side): [hi | lo | hi];  wmode 1 (W side): [hi | hi | lo]
// ---------------------------------------------------------------------------
__device__ __forceinline__ void split3_body(const float* __restrict__ in,
                                            short* __restrict__ out, int wmode) {
  int r = blockIdx.x;
  int c = threadIdx.x << 2;
  float4 v = *(const float4*)(in + (size_t)r * 1024 + c);
  short4v hi, lo;
  hi.x = f2bf(v.x); lo.x = f2bf(v.x - bf2f(hi.x));
  hi.y = f2bf(v.y); lo.y = f2bf(v.y - bf2f(hi.y));
  hi.z = f2bf(v.z); lo.z = f2bf(v.z - bf2f(hi.z));
  hi.w = f2bf(v.w); lo.w = f2bf(v.w - bf2f(hi.w));
  *(short4v*)(out + (size_t)r * 3072 + c) = hi;
  if (wmode == 0) {
    *(short4v*)(out + (size_t)r * 3072 + 1024 + c) = lo;
    *(short4v*)(out + (size_t)r * 3072 + 2048 + c) = hi;
  } else {
    *(short4v*)(out + (size_t)r * 3072 + 1024 + c) = hi;
    *(short4v*)(out + (size_t)r * 3072 + 2048 + c) = lo;
  }
}

__global__ __launch_bounds__(256)
void split3_convert(const float* __restrict__ in, short* __restrict__ out,
                    int total4, int wmode) {
  (void)total4;
  split3_body(in, out, wmode);
}

struct PrepArgs {
  const float* x0; short* xs0;
  const float* x1; short* xs1;
  const float* x2; short* xs2;
  const float* w0; short* wsd0;
  const float* w1; short* wsd1;
  const float* w2; short* wsd2;
  const float* w3; short* wsd3;
  const float* pe; short* peT;
};

// z 0..2: activations (2048 rows, wmode 0); z 3..6: weights (1024 rows, wmode 1);
// z 7: pe transpose (block 0 only).
__global__ __launch_bounds__(256)
void prep_all(PrepArgs P) {
  const int z = blockIdx.z;
  if (z < 3) {
    const float* in = (z == 0) ? P.x0 : (z == 1 ? P.x1 : P.x2);
    short* out = (z == 0) ? P.xs0 : (z == 1 ? P.xs1 : P.xs2);
    split3_body(in, out, 0);
  } else if (z < 7) {
    if (blockIdx.x >= 1024) return;
    const float* in = (z == 3) ? P.w0 : (z == 4 ? P.w1 : (z == 5 ? P.w2 : P.w3));
    short* out = (z == 3) ? P.wsd0 : (z == 4 ? P.wsd1 : (z == 5 ? P.wsd2 : P.wsd3));
    split3_body(in, out, 1);
  } else {
    if (blockIdx.x != 0) return;
    for (int i = threadIdx.x; i < 4096; i += 256) {
      int n = i >> 6, d = i & 63;
      P.peT[n * 64 + d] = f2bf(P.pe[d * 64 + n]);   // peT[npos][d]
    }
  }
}

__global__ __launch_bounds__(256)
void pe_transpose(const float* __restrict__ pe, short* __restrict__ peT) {
  for (int i = threadIdx.x; i < 4096; i += 256) {
    int n = i >> 6, d = i & 63;
    peT[n * 64 + d] = f2bf(pe[d * 64 + n]);
  }
}

// ---------------------------------------------------------------------------
// Split-bf16 MFMA GEMM args (shared by both tile variants)
// mode 0: fp32 out [M][1024]
// mode 1: head split bf16: o0/o1 = hi/lo at [h][m][64]
// mode 2: head transposed split: hi/lo at [h][64][m]
// ---------------------------------------------------------------------------
struct GArg {
  const short* X; const short* W; const float* bias;
  void* o0; void* o1; int mode;
};

__device__ __forceinline__ void gemm_epilogue_store(const GArg& A, int m, int n, float v) {
  if (A.mode == 0) {
    ((float*)A.o0)[(size_t)m * 1024 + n] = v;
  } else {
    short hi = f2bf(v), lo = f2bf(v - bf2f(hi));
    const int hh = n >> 6, d = n & 63;
    size_t off = (A.mode == 1) ? ((size_t)(hh * SEQ + m) * 64 + d)
                               : ((size_t)(hh * 64 + d) * SEQ + m);
    ((short*)A.o0)[off] = hi;
    ((short*)A.o1)[off] = lo;
  }
}

// 128x128 tile (used by MID fallback path)
__global__ __launch_bounds__(256)
void gemm_split(GArg ga, GArg gb, GArg gc) {
  __shared__ __align__(16) short As[4096];
  __shared__ __align__(16) short Bs[4096];
  GArg A = (blockIdx.z == 0) ? ga : ((blockIdx.z == 1) ? gb : gc);
  const int t = threadIdx.x;
  const int w = t >> 6, lane = t & 63;
  const int col = lane & 15, quad = lane >> 4;
  const int m0 = blockIdx.x * 128, n0 = blockIdx.y * 128;
  const int wr = (w & 1) * 64, wc = (w >> 1) * 64;
  const int srow = lane >> 2, scs = lane & 3;
  floatx4 acc[4][4] = {};
  for (int kk = 0; kk < 3072; kk += 32) {
#pragma unroll
    for (int c = 0; c < 2; ++c) {
      int rowA = w * 32 + c * 16 + srow;
      int gch = scs ^ ((rowA >> 1) & 3);
      ASYNC16(A.X + (size_t)(m0 + rowA) * 3072 + kk + gch * 8, &As[(w * 32 + c * 16) * 32]);
      ASYNC16(A.W + (size_t)(n0 + rowA) * 3072 + kk + gch * 8, &Bs[(w * 32 + c * 16) * 32]);
    }
    __syncthreads();
    short8 af[4], bfr[4];
#pragma unroll
    for (int mt = 0; mt < 4; ++mt) {
      int row = wr + mt * 16 + col;
      af[mt] = *(const short8*)&As[row * 32 + ((quad ^ ((row >> 1) & 3)) & 3) * 8];
    }
#pragma unroll
    for (int nt = 0; nt < 4; ++nt) {
      int row = wc + nt * 16 + col;
      bfr[nt] = *(const short8*)&Bs[row * 32 + ((quad ^ ((row >> 1) & 3)) & 3) * 8];
    }
#pragma unroll
    for (int mt = 0; mt < 4; ++mt)
#pragma unroll
      for (int nt = 0; nt < 4; ++nt)
        acc[mt][nt] = MFMA16(af[mt], bfr[nt], acc[mt][nt]);
    __syncthreads();
  }
#pragma unroll
  for (int nt = 0; nt < 4; ++nt) {
    const int n = n0 + wc + nt * 16 + col;
    const float bb = A.bias[n];
#pragma unroll
    for (int mt = 0; mt < 4; ++mt)
#pragma unroll
      for (int r = 0; r < 4; ++r)
        gemm_epilogue_store(A, m0 + wr + mt * 16 + quad * 4 + r, n, acc[mt][nt][r] + bb);
  }
}

// 128x64 tile — 2x the blocks for CU load balance (768 QKV / 256 final)
__global__ __launch_bounds__(256)
void gemm_split64(GArg ga, GArg gb, GArg gc) {
  __shared__ __align__(16) short As[4096];   // 128 rows x 32 k
  __shared__ __align__(16) short Bs[2048];   // 64 rows x 32 k
  GArg A = (blockIdx.z == 0) ? ga : ((blockIdx.z == 1) ? gb : gc);
  const int t = threadIdx.x;
  const int w = t >> 6, lane = t & 63;
  const int col = lane & 15, quad = lane >> 4;
  const int m0 = blockIdx.x * 128, n0 = blockIdx.y * 64;
  const int wr = (w & 1) * 64, wc = (w >> 1) * 32;
  const int srow = lane >> 2, scs = lane & 3;
  floatx4 acc[4][2] = {};
  for (int kk = 0; kk < 3072; kk += 32) {
#pragma unroll
    for (int c = 0; c < 2; ++c) {
      int rowA = w * 32 + c * 16 + srow;
      int gch = scs ^ ((rowA >> 1) & 3);
      ASYNC16(A.X + (size_t)(m0 + rowA) * 3072 + kk + gch * 8, &As[(w * 32 + c * 16) * 32]);
    }
    {
      int rowB = w * 16 + srow;
      int gch = scs ^ ((rowB >> 1) & 3);
      ASYNC16(A.W + (size_t)(n0 + rowB) * 3072 + kk + gch * 8, &Bs[(w * 16) * 32]);
    }
    __syncthreads();
    short8 af[4], bfr[2];
#pragma unroll
    for (int mt = 0; mt < 4; ++mt) {
      int row = wr + mt * 16 + col;
      af[mt] = *(const short8*)&As[row * 32 + ((quad ^ ((row >> 1) & 3)) & 3) * 8];
    }
#pragma unroll
    for (int nt = 0; nt < 2; ++nt) {
      int row = wc + nt * 16 + col;
      bfr[nt] = *(const short8*)&Bs[row * 32 + ((quad ^ ((row >> 1) & 3)) & 3) * 8];
    }
#pragma unroll
    for (int mt = 0; mt < 4; ++mt)
#pragma unroll
      for (int nt = 0; nt < 2; ++nt)
        acc[mt][nt] = MFMA16(af[mt], bfr[nt], acc[mt][nt]);
    __syncthreads();
  }
#pragma unroll
  for (int nt = 0; nt < 2; ++nt) {
    const int n = n0 + wc + nt * 16 + col;
    const float bb = A.bias[n];
#pragma unroll
    for (int mt = 0; mt < 4; ++mt)
#pragma unroll
      for (int r = 0; r < 4; ++r)
        gemm_epilogue_store(A, m0 + wr + mt * 16 + quad * 4 + r, n, acc[mt][nt][r] + bb);
  }
}

// ---------------------------------------------------------------------------
// Flash CoPE attention v4. 256-thr blocks = 4 waves x 16 q-rows (64-q block).
// K/V tiles LDS-staged via DMA (double-buffered, XOR-swizzled). Key tiles
// last->first. CLAMP FAST-PATH: once carry >= 63 (all rows), every remaining
// pos clamps to 63 exactly -> p = exp(s + lis[63]); the gate/scan/interp
// machinery is skipped (~29 of 32 tiles).
// QK: A=K_hi, B=Q_split -> D[key=quad*4+r][qrow=col]
// PV: A=P_hi (LDS transpose), B=V_hi^T -> D[qrow=quad*4+r][d=col+16dt]
// ---------------------------------------------------------------------------
__global__ __launch_bounds__(256, 2)
void cope_attn_mfma(const short* __restrict__ Qhi, const short* __restrict__ Qlo,
                    const short* __restrict__ Khi, const short* __restrict__ Vthi,
                    const short* __restrict__ peT, short* __restrict__ AOs) {
  __shared__ __align__(16) short Klds[2][4096];   // [buf][row 0..63][chunk^swz]
  __shared__ __align__(16) short Vlds[2][4096];   // [buf][d 0..63][chunk^swz]
  __shared__ __align__(16) short Phi[4][16][72];  // per-wave P transpose
  __shared__ float2 lis2[4][16][65];              // per-wave (lis[p], lis[p+1])
  const int tid = threadIdx.x;
  const int w = tid >> 6, lane = tid & 63;
  const int col = lane & 15, quad = lane >> 4;
  const int h = blockIdx.x & 15;
  const int q0 = (blockIdx.x >> 4) * 64 + w * 16;

  const short* Kb = Khi + (size_t)h * SEQ * 64;
  const short* Vb = Vthi + (size_t)h * 64 * SEQ;

  const int lrow8 = lane >> 3;                 // 0..7
  const int src_c = (lane & 7) ^ lrow8;        // XOR-swizzled source chunk

  auto stage = [&](int kt, int buf) {
#pragma unroll
    for (int i = 0; i < 2; ++i) {
      const int inst = 2 * w + i;
      const int row = inst * 8 + lrow8;
      ASYNC16(Kb + (size_t)(kt * 64 + row) * 64 + src_c * 8, &Klds[buf][inst * 512]);
      ASYNC16(Vb + (size_t)row * SEQ + kt * 64 + src_c * 8, &Vlds[buf][inst * 512]);
    }
  };

  short8 qB[2][2];
#pragma unroll
  for (int ks = 0; ks < 2; ++ks) {
    qB[ks][0] = *(const short8*)(Qhi + (size_t)(h * SEQ + q0 + col) * 64 + ks * 32 + quad * 8);
    qB[ks][1] = *(const short8*)(Qlo + (size_t)(h * SEQ + q0 + col) * 64 + ks * 32 + quad * 8);
  }

  stage(31, 0);

  // logits_int = Q · pos_emb (full split) -> D[qrow=quad*4+r][npos=col+16nt]
  {
    floatx4 li[4] = {};
#pragma unroll
    for (int nt = 0; nt < 4; ++nt)
#pragma unroll
      for (int ks = 0; ks < 2; ++ks) {
        short8 pb = *(const short8*)(peT + (nt * 16 + col) * 64 + ks * 32 + quad * 8);
        li[nt] = MFMA16(qB[ks][0], pb, li[nt]);
        li[nt] = MFMA16(qB[ks][1], pb, li[nt]);
      }
#pragma unroll
    for (int nt = 0; nt < 4; ++nt)
#pragma unroll
      for (int r = 0; r < 4; ++r) {
        const int qr = quad * 4 + r;
        const int pos = nt * 16 + col;
        const float v = li[nt][r];
        lis2[w][qr][pos].x = v;
        if (pos > 0) lis2[w][qr][pos - 1].y = v;
        if (pos == 63) lis2[w][qr][63].y = v;
      }
  }
  __syncthreads();   // staging(31) drained + lis2 ready
  const float lis63 = lis2[w][col][63].x;   // q-row = col

  float lrow = 0.f;
  float carry = 0.f;
  bool fast = false;
  floatx4 O[4] = {};

  const int swz = col & 7;

#pragma unroll 1
  for (int it = 0; it < 32; ++it) {
    const int kt = 31 - it;
    const int buf = it & 1;
    if (kt > 0) stage(kt - 1, buf ^ 1);

    short8 kf[4][2], vf[2][4];
#pragma unroll
    for (int ksub = 0; ksub < 4; ++ksub)
#pragma unroll
      for (int ks = 0; ks < 2; ++ks)
        kf[ksub][ks] =
            *(const short8*)&Klds[buf][(ksub * 16 + col) * 64 + (((ks * 4 + quad) ^ swz) * 8)];
#pragma unroll
    for (int ks = 0; ks < 2; ++ks)
#pragma unroll
      for (int dt = 0; dt < 4; ++dt)
        vf[ks][dt] =
            *(const short8*)&Vlds[buf][(dt * 16 + col) * 64 + (((ks * 4 + quad) ^ swz) * 8)];

    // QK (K hi · Q split)
    floatx4 S[4] = {};
#pragma unroll
    for (int ksub = 0; ksub < 4; ++ksub)
#pragma unroll
      for (int ks = 0; ks < 2; ++ks) {
        S[ksub] = MFMA16(kf[ksub][ks], qB[ks][0], S[ksub]);
        S[ksub] = MFMA16(kf[ksub][ks], qB[ks][1], S[ksub]);
      }
    float sv[4][4];
#pragma unroll
    for (int ksub = 0; ksub < 4; ++ksub)
#pragma unroll
      for (int r = 0; r < 4; ++r) sv[ksub][r] = S[ksub][r] * 0.125f;

    if (!fast && __all((int)(carry >= 63.0f))) fast = true;

    float p4[4][4];
    if (fast) {
      // pos clamps to exactly 63 for every element: cope = lis[63]
#pragma unroll
      for (int ksub = 0; ksub < 4; ++ksub)
#pragma unroll
        for (int r = 0; r < 4; ++r) {
          float pr = __expf(sv[ksub][r] + lis63);
          p4[ksub][r] = pr;
          lrow += pr;
        }
    } else {
      float g[4][4];
#pragma unroll
      for (int ksub = 0; ksub < 4; ++ksub)
#pragma unroll
        for (int r = 0; r < 4; ++r)
          g[ksub][r] = __builtin_amdgcn_rcpf(1.0f + __expf(-sv[ksub][r]));
      // suffix-scan: all shuffles independent -> single DS latency hop
      float l[4][4], S4[4];
#pragma unroll
      for (int ksub = 0; ksub < 4; ++ksub) {
        l[ksub][3] = g[ksub][3];
        l[ksub][2] = l[ksub][3] + g[ksub][2];
        l[ksub][1] = l[ksub][2] + g[ksub][1];
        l[ksub][0] = l[ksub][1] + g[ksub][0];
        S4[ksub] = l[ksub][0];
      }
      float Sq[4], T[4];
#pragma unroll
      for (int ksub = 0; ksub < 4; ++ksub) {
        float d16 = __shfl_down(S4[ksub], 16, 64);
        float d32 = __shfl_down(S4[ksub], 32, 64);
        float d48 = __shfl_down(S4[ksub], 48, 64);
        float u16 = __shfl_up(S4[ksub], 16, 64);
        float u32 = __shfl_up(S4[ksub], 32, 64);
        float u48 = __shfl_up(S4[ksub], 48, 64);
        float sq = ((quad < 3) ? d16 : 0.f) + ((quad < 2) ? d32 : 0.f) + ((quad < 1) ? d48 : 0.f);
        float pq = ((quad > 0) ? u16 : 0.f) + ((quad > 1) ? u32 : 0.f) + ((quad > 2) ? u48 : 0.f);
        Sq[ksub] = sq;
        T[ksub] = pq + S4[ksub] + sq;
      }
      float U[4];
      U[3] = carry;
      U[2] = U[3] + T[3];
      U[1] = U[2] + T[2];
      U[0] = U[1] + T[1];
      carry = U[0] + T[0];
      // CoPE interp + exp (no max subtraction)
#pragma unroll
      for (int ksub = 0; ksub < 4; ++ksub)
#pragma unroll
        for (int r = 0; r < 4; ++r) {
          float p = fminf(U[ksub] + Sq[ksub] + l[ksub][r], 63.0f);
          float pf = floorf(p);
          int fi = (int)pf;
          float wq = p - pf;
          float2 lfc = lis2[w][col][fi];
          float pr = __expf(sv[ksub][r] + lfc.x + wq * (lfc.y - lfc.x));
          p4[ksub][r] = pr;
          lrow += pr;
        }
    }
    // P: D-layout -> A-layout through LDS (per-wave buffer, wave-ordered)
#pragma unroll
    for (int ksub = 0; ksub < 4; ++ksub)
#pragma unroll
      for (int rp = 0; rp < 2; ++rp) {
        short h0 = f2bf(p4[ksub][2 * rp]);
        short h1 = f2bf(p4[ksub][2 * rp + 1]);
        *(int*)&Phi[w][col][ksub * 16 + quad * 4 + 2 * rp] =
            (unsigned short)h0 | ((unsigned)(unsigned short)h1 << 16);
      }
    short8 pa[2];
#pragma unroll
    for (int ks = 0; ks < 2; ++ks)
      pa[ks] = *(const short8*)&Phi[w][col][ks * 32 + quad * 8];
    // PV (bf16-only)
#pragma unroll
    for (int ks = 0; ks < 2; ++ks)
#pragma unroll
      for (int dt = 0; dt < 4; ++dt)
        O[dt] = MFMA16(pa[ks], vf[ks][dt], O[dt]);

    __syncthreads();   // all waves done with buf; stage(kt-1) drained here
  }

  // epilogue: reduce lrow (deferred), normalize, write split AO
  float lr = lrow;
  lr += __shfl_xor(lr, 16, 64);
  lr += __shfl_xor(lr, 32, 64);
  float inv[4];
#pragma unroll
  for (int r = 0; r < 4; ++r) inv[r] = 1.0f / __shfl(lr, quad * 4 + r, 64);
#pragma unroll
  for (int dt = 0; dt < 4; ++dt)
#pragma unroll
    for (int r = 0; r < 4; ++r) {
      float val = O[dt][r] * inv[r];
      int q = q0 + quad * 4 + r;
      int cg = h * 64 + dt * 16 + col;
      short hi = f2bf(val), lo = f2bf(val - bf2f(hi));
      AOs[(size_t)q * 3072 + cg] = hi;
      AOs[(size_t)q * 3072 + 1024 + cg] = lo;
      AOs[(size_t)q * 3072 + 2048 + cg] = hi;
    }
}

// ---------------------------------------------------------------------------
// Round-1 proven fp32 fallback (used only if ws_size is too small)
// ---------------------------------------------------------------------------
template <int MODE>
__global__ __launch_bounds__(256)
void gemm_bt_f32(const float* __restrict__ X, const float* __restrict__ W,
                 const float* __restrict__ bias, float* __restrict__ C,
                 int M, int N, int K) {
  __shared__ __align__(16) float Xs[16][68];
  __shared__ __align__(16) float Ws[16][68];
  const int t = threadIdx.x;
  const int tx = t & 15, ty = t >> 4;
  const int m0 = blockIdx.x * 64, n0 = blockIdx.y * 64;
  const int r = t >> 2;
  const int c4 = (t & 3) << 2;
  const float* Xp = X + (size_t)(m0 + r) * K + c4;
  const float* Wp = W + (size_t)(n0 + r) * K + c4;
  float acc[4][4] = {};
  for (int k0 = 0; k0 < K; k0 += 16) {
    float4 xv = *(const float4*)(Xp + k0);
    float4 wv = *(const float4*)(Wp + k0);
    __syncthreads();
    Xs[c4 + 0][r] = xv.x; Xs[c4 + 1][r] = xv.y; Xs[c4 + 2][r] = xv.z; Xs[c4 + 3][r] = xv.w;
    Ws[c4 + 0][r] = wv.x; Ws[c4 + 1][r] = wv.y; Ws[c4 + 2][r] = wv.z; Ws[c4 + 3][r] = wv.w;
    __syncthreads();
#pragma unroll
    for (int k = 0; k < 16; ++k) {
      const float4 xr = *(const float4*)&Xs[k][ty << 2];
      const float4 wr = *(const float4*)&Ws[k][tx << 2];
      const float xa[4] = {xr.x, xr.y, xr.z, xr.w};
      const float wa[4] = {wr.x, wr.y, wr.z, wr.w};
#pragma unroll
      for (int i = 0; i < 4; ++i)
#pragma unroll
        for (int j = 0; j < 4; ++j) acc[i][j] += xa[i] * wa[j];
    }
  }
#pragma unroll
  for (int i = 0; i < 4; ++i) {
    const int m = m0 + (ty << 2) + i;
#pragma unroll
    for (int j = 0; j < 4; ++j) {
      const int n = n0 + (tx << 2) + j;
      const float v = acc[i][j] + bias[n];
      if (MODE == 0) C[(size_t)m * N + n] = v;
      else { const int hh = n >> 6, d = n & 63; C[((size_t)hh * SEQ + m) * HD + d] = v; }
    }
  }
}

__global__ __launch_bounds__(256)
void cope_attn_f32(const float* __restrict__ Qh, const float* __restrict__ Kh,
                   const float* __restrict__ Vh, const float* __restrict__ pe,
                   float* __restrict__ AO) {
  __shared__ float Kt[64][65];
  __shared__ float Vt[64][65];
  __shared__ float lis[16][64];
  const int t = threadIdx.x;
  const int lane = t & 63;
  const int w = t >> 6;
  const int h = blockIdx.y;
  const int qbase = blockIdx.x * 16 + w * 4;
  float qreg[4];
#pragma unroll
  for (int rr = 0; rr < 4; ++rr)
    qreg[rr] = Qh[((size_t)h * SEQ + qbase + rr) * HD + lane];
  float li[4] = {0.f, 0.f, 0.f, 0.f};
  for (int d = 0; d < 64; ++d) {
    const float pv = pe[d * NPOSN + lane];
#pragma unroll
    for (int rr = 0; rr < 4; ++rr) li[rr] += lane_bcast(qreg[rr], d) * pv;
  }
#pragma unroll
  for (int rr = 0; rr < 4; ++rr) lis[w * 4 + rr][lane] = li[rr];
  float mrow[4] = {-1e30f, -1e30f, -1e30f, -1e30f};
  float lrow[4] = {0.f, 0.f, 0.f, 0.f};
  float carry[4] = {0.f, 0.f, 0.f, 0.f};
  float acc[4] = {0.f, 0.f, 0.f, 0.f};
  for (int kt = (SEQ / 64) - 1; kt >= 0; --kt) {
    const int k0 = kt * 64;
    __syncthreads();
#pragma unroll
    for (int i = 0; i < 4; ++i) {
      const int lin = t + i * 256;
      const int row = lin >> 4, cc = (lin & 15) << 2;
      const float4 kv = *(const float4*)(Kh + ((size_t)h * SEQ + k0 + row) * HD + cc);
      Kt[row][cc + 0] = kv.x; Kt[row][cc + 1] = kv.y; Kt[row][cc + 2] = kv.z; Kt[row][cc + 3] = kv.w;
      const float4 vv = *(const float4*)(Vh + ((size_t)h * SEQ + k0 + row) * HD + cc);
      Vt[row][cc + 0] = vv.x; Vt[row][cc + 1] = vv.y; Vt[row][cc + 2] = vv.z; Vt[row][cc + 3] = vv.w;
    }
    __syncthreads();
    float svv[4] = {0.f, 0.f, 0.f, 0.f};
#pragma unroll
    for (int d = 0; d < 64; ++d) {
      const float kd = Kt[lane][d];
#pragma unroll
      for (int rr = 0; rr < 4; ++rr) svv[rr] += lane_bcast(qreg[rr], d) * kd;
    }
    float p4[4], scl[4];
#pragma unroll
    for (int rr = 0; rr < 4; ++rr) {
      const float s = svv[rr] * 0.125f;
      const float gg = 1.0f / (1.0f + __expf(-s));
      float gs = gg;
#pragma unroll
      for (int off = 1; off < 64; off <<= 1) {
        const float tt = __shfl_down(gs, off, 64);
        gs += (lane + off < 64) ? tt : 0.0f;
      }
      const float tot = lane_bcast(gs, 0);
      float p = carry[rr] + gs;
      carry[rr] += tot;
      p = fminf(p, 63.0f);
      const float pf = floorf(p);
      const float wq = p - pf;
      const int fi = (int)pf;
      const int ci = (int)ceilf(p);
      const float cope = lis[w * 4 + rr][ci] * wq + lis[w * 4 + rr][fi] * (1.0f - wq);
      const float av = s + cope;
      float mt = av;
#pragma unroll
      for (int off = 32; off > 0; off >>= 1) mt = fmaxf(mt, __shfl_xor(mt, off, 64));
      const float nm = fmaxf(mrow[rr], mt);
      const float sc = __expf(mrow[rr] - nm);
      const float p2 = __expf(av - nm);
      float psum = p2;
#pragma unroll
      for (int off = 32; off > 0; off >>= 1) psum += __shfl_xor(psum, off, 64);
      lrow[rr] = lrow[rr] * sc + psum;
      mrow[rr] = nm;
      p4[rr] = p2;
      scl[rr] = sc;
    }
#pragma unroll
    for (int rr = 0; rr < 4; ++rr) acc[rr] *= scl[rr];
#pragma unroll
    for (int j = 0; j < 64; ++j) {
      const float vj = Vt[j][lane];
#pragma unroll
      for (int rr = 0; rr < 4; ++rr) acc[rr] += lane_bcast(p4[rr], j) * vj;
    }
  }
#pragma unroll
  for (int rr = 0; rr < 4; ++rr)
    AO[(size_t)(qbase + rr) * ND + h * HD + lane] = acc[rr] / lrow[rr];
}

// ---------------------------------------------------------------------------
extern "C" void kernel_launch(void* const* d_in, const int* in_sizes, int n_in,
                              void* d_out, int out_size, void* d_ws, size_t ws_size,
                              hipStream_t stream) {
  (void)in_sizes; (void)n_in; (void)out_size;
  const float* q    = (const float*)d_in[0];
  const float* k    = (const float*)d_in[1];
  const float* v    = (const float*)d_in[2];
  const float* Wq_w = (const float*)d_in[3];
  const float* Wq_b = (const float*)d_in[4];
  const float* Wk_w = (const float*)d_in[5];
  const float* Wk_b = (const float*)d_in[6];
  const float* Wv_w = (const float*)d_in[7];
  const float* Wv_b = (const float*)d_in[8];
  const float* Wo_w = (const float*)d_in[9];
  const float* Wo_b = (const float*)d_in[10];
  const float* pe   = (const float*)d_in[11];
  float* out = (float*)d_out;
  char* ws = (char*)d_ws;

  const size_t XSB = (size_t)SEQ * 3072 * 2;   // 12,582,912
  const size_t WSB = (size_t)1024 * 3072 * 2;  //  6,291,456
  const size_t HB  = (size_t)SEQ * 1024 * 2;   //  4,194,304
  const size_t FULL = 3 * XSB + 4 * WSB + 6 * HB + 8192;
  const size_t MID  = XSB + WSB + 6 * HB + 8192;

  if (ws_size >= FULL) {
    short* XSq = (short*)ws;
    short* XSk = (short*)(ws + XSB);
    short* XSv = (short*)(ws + 2 * XSB);
    short* WSq = (short*)(ws + 3 * XSB);
    short* WSk = (short*)(ws + 3 * XSB + WSB);
    short* WSv = (short*)(ws + 3 * XSB + 2 * WSB);
    short* WSo = (short*)(ws + 3 * XSB + 3 * WSB);
    char*  hb  = ws + 3 * XSB + 4 * WSB;
    short* Qhi = (short*)hb;             short* Qlo = (short*)(hb + HB);
    short* Khi = (short*)(hb + 2 * HB);  short* Klo = (short*)(hb + 3 * HB);
    short* Vthi = (short*)(hb + 4 * HB); short* Vtlo = (short*)(hb + 5 * HB);
    short* peT = (short*)(hb + 6 * HB);
    short* AOs = XSq;  // reuse after projections

    PrepArgs P{q, XSq, k, XSk, v, XSv, Wq_w, WSq, Wk_w, WSk, Wv_w, WSv, Wo_w, WSo, pe, peT};
    prep_all<<<dim3(2048, 1, 8), 256, 0, stream>>>(P);
    GArg aq{XSq, WSq, Wq_b, Qhi, Qlo, 1};
    GArg ak{XSk, WSk, Wk_b, Khi, Klo, 1};
    GArg av{XSv, WSv, Wv_b, Vthi, Vtlo, 2};
    gemm_split64<<<dim3(16, 16, 3), 256, 0, stream>>>(aq, ak, av);
    cope_attn_mfma<<<512, 256, 0, stream>>>(Qhi, Qlo, Khi, Vthi, peT, AOs);
    GArg ao{AOs, WSo, Wo_b, (void*)out, nullptr, 0};
    gemm_split64<<<dim3(16, 16, 1), 256, 0, stream>>>(ao, ao, ao);
  } else if (ws_size >= MID) {
    short* XS = (short*)ws;
    short* WS = (short*)(ws + XSB);
    char*  hb = ws + XSB + WSB;
    short* Qhi = (short*)hb;             short* Qlo = (short*)(hb + HB);
    short* Khi = (short*)(hb + 2 * HB);  short* Klo = (short*)(hb + 3 * HB);
    short* Vthi = (short*)(hb + 4 * HB); short* Vtlo = (short*)(hb + 5 * HB);
    short* peT = (short*)(hb + 6 * HB);
    short* AOs = XS;

    pe_transpose<<<1, 256, 0, stream>>>(pe, peT);
    split3_convert<<<2048, 256, 0, stream>>>(q, XS, 2048 * 256, 0);
    split3_convert<<<1024, 256, 0, stream>>>(Wq_w, WS, 1024 * 256, 1);
    { GArg a{XS, WS, Wq_b, Qhi, Qlo, 1}; gemm_split<<<dim3(16, 8, 1), 256, 0, stream>>>(a, a, a); }
    split3_convert<<<2048, 256, 0, stream>>>(k, XS, 2048 * 256, 0);
    split3_convert<<<1024, 256, 0, stream>>>(Wk_w, WS, 1024 * 256, 1);
    { GArg a{XS, WS, Wk_b, Khi, Klo, 1}; gemm_split<<<dim3(16, 8, 1), 256, 0, stream>>>(a, a, a); }
    split3_convert<<<2048, 256, 0, stream>>>(v, XS, 2048 * 256, 0);
    split3_convert<<<1024, 256, 0, stream>>>(Wv_w, WS, 1024 * 256, 1);
    { GArg a{XS, WS, Wv_b, Vthi, Vtlo, 2}; gemm_split<<<dim3(16, 8, 1), 256, 0, stream>>>(a, a, a); }
    cope_attn_mfma<<<512, 256, 0, stream>>>(Qhi, Qlo, Khi, Vthi, peT, AOs);
    split3_convert<<<1024, 256, 0, stream>>>(Wo_w, WS, 1024 * 256, 1);
    { GArg a{AOs, WS, Wo_b, (void*)out, nullptr, 0}; gemm_split<<<dim3(16, 8, 1), 256, 0, stream>>>(a, a, a); }
  } else {
    const size_t per = (size_t)NH * SEQ * HD;
    float* Qh = (float*)d_ws;
    float* Kh = Qh + per;
    float* Vh = Kh + per;
    float* AO = Vh + per;
    dim3 gblk(256), ggrd(SEQ / 64, ND / 64);
    gemm_bt_f32<1><<<ggrd, gblk, 0, stream>>>(q, Wq_w, Wq_b, Qh, SEQ, ND, ND);
    gemm_bt_f32<1><<<ggrd, gblk, 0, stream>>>(k, Wk_w, Wk_b, Kh, SEQ, ND, ND);
    gemm_bt_f32<1><<<ggrd, gblk, 0, stream>>>(v, Wv_w, Wv_b, Vh, SEQ, ND, ND);
    cope_attn_f32<<<dim3(SEQ / 16, NH), 256, 0, stream>>>(Qh, Kh, Vh, pe, AO);
    gemm_bt_f32<0><<<ggrd, gblk, 0, stream>>>(AO, Wo_w, Wo_b, out, SEQ, ND, ND);
  }
}

// Round 7
// 209.120 us; speedup vs baseline: 5.1721x; 1.3027x over previous
//
#include <hip/hip_runtime.h>
#include <hip/hip_bf16.h>
#include <math.h>

#define SEQ 2048
#define ND  1024
#define NH  16
#define HD  64
#define NPOSN 64

typedef short short8 __attribute__((ext_vector_type(8)));
typedef short short4v __attribute__((ext_vector_type(4)));
typedef float floatx4 __attribute__((ext_vector_type(4)));

#define MFMA16(A, B, C) __builtin_amdgcn_mfma_f32_16x16x32_bf16((A), (B), (C), 0, 0, 0)

#define ASYNC16(gp, lp)                                                                     \
  __builtin_amdgcn_global_load_lds((const __attribute__((address_space(1))) unsigned int*)(gp), \
                                   (__attribute__((address_space(3))) unsigned int*)(lp), 16, 0, 0)

__device__ __forceinline__ short f2bf(float x) {
  __hip_bfloat16 h = __float2bfloat16(x);
  return *reinterpret_cast<short*>(&h);
}
__device__ __forceinline__ float bf2f(short s) {
  __hip_bfloat16 h = *reinterpret_cast<__hip_bfloat16*>(&s);
  return __bfloat162float(h);
}
__device__ __forceinline__ float lane_bcast(float v, int l) {
  return __int_as_float(__builtin_amdgcn_readlane(__float_as_int(v), l));
}

// ---------------------------------------------------------------------------
// prep: fp32 -> separate bf16 hi/lo planes (K=1024 rows).
// z 0..2: activations q,k,v (2048 rows); z 3..6: weights (1024 rows); z 7: peT.
// ---------------------------------------------------------------------------
struct Prep2 {
  const float* x0; short* x0h; short* x0l;
  const float* x1; short* x1h; short* x1l;
  const float* x2; short* x2h; short* x2l;
  const float* w0; short* w0h; short* w0l;
  const float* w1; short* w1h; short* w1l;
  const float* w2; short* w2h; short* w2l;
  const float* w3; short* w3h; short* w3l;
  const float* pe; short* peT;
};

__device__ __forceinline__ void split_planes(const float* __restrict__ in,
                                             short* __restrict__ oh,
                                             short* __restrict__ ol) {
  int r = blockIdx.x;
  int c = threadIdx.x << 2;
  float4 v = *(const float4*)(in + (size_t)r * 1024 + c);
  short4v hi, lo;
  hi.x = f2bf(v.x); lo.x = f2bf(v.x - bf2f(hi.x));
  hi.y = f2bf(v.y); lo.y = f2bf(v.y - bf2f(hi.y));
  hi.z = f2bf(v.z); lo.z = f2bf(v.z - bf2f(hi.z));
  hi.w = f2bf(v.w); lo.w = f2bf(v.w - bf2f(hi.w));
  *(short4v*)(oh + (size_t)r * 1024 + c) = hi;
  *(short4v*)(ol + (size_t)r * 1024 + c) = lo;
}

__global__ __launch_bounds__(256)
void prep2(Prep2 P) {
  const int z = blockIdx.z;
  if (z < 3) {
    const float* in = (z == 0) ? P.x0 : (z == 1 ? P.x1 : P.x2);
    short* oh = (z == 0) ? P.x0h : (z == 1 ? P.x1h : P.x2h);
    short* ol = (z == 0) ? P.x0l : (z == 1 ? P.x1l : P.x2l);
    split_planes(in, oh, ol);
  } else if (z < 7) {
    if (blockIdx.x >= 1024) return;
    const float* in = (z == 3) ? P.w0 : (z == 4 ? P.w1 : (z == 5 ? P.w2 : P.w3));
    short* oh = (z == 3) ? P.w0h : (z == 4 ? P.w1h : (z == 5 ? P.w2h : P.w3h));
    short* ol = (z == 3) ? P.w0l : (z == 4 ? P.w1l : (z == 5 ? P.w2l : P.w3l));
    split_planes(in, oh, ol);
  } else {
    if (blockIdx.x != 0) return;
    for (int i = threadIdx.x; i < 4096; i += 256) {
      int n = i >> 6, d = i & 63;
      P.peT[n * 64 + d] = f2bf(P.pe[d * 64 + n]);   // peT[npos][d]
    }
  }
}

// ---------------------------------------------------------------------------
// Plane-split MFMA GEMM: C[M,N] = X[M,1024]·W[N,1024]^T + bias, split-bf16.
// 3-term (Blo != null): Ahi·Bhi + Alo·Bhi + Ahi·Blo  (~2^-18 rel err)
// 2-term (Blo == null): Ahi·Bhi + Alo·Bhi = exact-X · Whi (output used as bf16)
// Tile 128x64, BK=64, LDS DMA staging with XOR chunk swizzle (8x16B chunks/row).
// mode 0: fp32 out [M][1024]; mode 1: head bf16 o0(/o1) at [h][m][64];
// mode 2: head transposed at [h][64][m].  o1==null -> skip lo store.
// ---------------------------------------------------------------------------
struct GArg2 {
  const short* Ahi; const short* Alo;
  const short* Bhi; const short* Blo;
  const float* bias;
  void* o0; void* o1; int mode;
};

__global__ __launch_bounds__(256, 3)
void gemm_planes(GArg2 ga, GArg2 gb, GArg2 gc) {
  __shared__ __align__(16) short Ah[8192];   // 128 rows x 64 k
  __shared__ __align__(16) short Al[8192];
  __shared__ __align__(16) short Bh[4096];   // 64 rows x 64 k
  __shared__ __align__(16) short Bl[4096];
  GArg2 A = (blockIdx.z == 0) ? ga : ((blockIdx.z == 1) ? gb : gc);
  const bool t3 = (A.Blo != nullptr);
  const int t = threadIdx.x;
  const int w = t >> 6, lane = t & 63;
  const int col = lane & 15, quad = lane >> 4;
  const int m0 = blockIdx.x * 128, n0 = blockIdx.y * 64;
  const int wr = (w & 1) * 64, wc = (w >> 1) * 32;
  const int lrow8 = lane >> 3;
  const int src_c = (lane & 7) ^ lrow8;      // XOR-swizzled source chunk

  floatx4 acc[4][2] = {};
  for (int kk = 0; kk < 1024; kk += 64) {
#pragma unroll
    for (int i = 0; i < 4; ++i) {
      const int inst = 4 * w + i;
      const int row = inst * 8 + lrow8;
      ASYNC16(A.Ahi + (size_t)(m0 + row) * 1024 + kk + src_c * 8, &Ah[inst * 512]);
      ASYNC16(A.Alo + (size_t)(m0 + row) * 1024 + kk + src_c * 8, &Al[inst * 512]);
    }
#pragma unroll
    for (int i = 0; i < 2; ++i) {
      const int inst = 2 * w + i;
      const int row = inst * 8 + lrow8;
      ASYNC16(A.Bhi + (size_t)(n0 + row) * 1024 + kk + src_c * 8, &Bh[inst * 512]);
      if (t3) ASYNC16(A.Blo + (size_t)(n0 + row) * 1024 + kk + src_c * 8, &Bl[inst * 512]);
    }
    __syncthreads();
#pragma unroll
    for (int ks = 0; ks < 2; ++ks) {
      short8 ah[4], al[4], bh[2], bl[2];
#pragma unroll
      for (int mt = 0; mt < 4; ++mt) {
        const int row = wr + mt * 16 + col;
        const int pos = ((ks * 4 + quad) ^ (row & 7)) * 8;
        ah[mt] = *(const short8*)&Ah[row * 64 + pos];
        al[mt] = *(const short8*)&Al[row * 64 + pos];
      }
#pragma unroll
      for (int nt = 0; nt < 2; ++nt) {
        const int row = wc + nt * 16 + col;
        const int pos = ((ks * 4 + quad) ^ (row & 7)) * 8;
        bh[nt] = *(const short8*)&Bh[row * 64 + pos];
        if (t3) bl[nt] = *(const short8*)&Bl[row * 64 + pos];
      }
#pragma unroll
      for (int mt = 0; mt < 4; ++mt)
#pragma unroll
        for (int nt = 0; nt < 2; ++nt) {
          acc[mt][nt] = MFMA16(ah[mt], bh[nt], acc[mt][nt]);
          acc[mt][nt] = MFMA16(al[mt], bh[nt], acc[mt][nt]);
          if (t3) acc[mt][nt] = MFMA16(ah[mt], bl[nt], acc[mt][nt]);
        }
    }
    __syncthreads();
  }
#pragma unroll
  for (int nt = 0; nt < 2; ++nt) {
    const int n = n0 + wc + nt * 16 + col;
    const float bb = A.bias[n];
#pragma unroll
    for (int mt = 0; mt < 4; ++mt)
#pragma unroll
      for (int r = 0; r < 4; ++r) {
        const int m = m0 + wr + mt * 16 + quad * 4 + r;
        const float v = acc[mt][nt][r] + bb;
        if (A.mode == 0) {
          ((float*)A.o0)[(size_t)m * 1024 + n] = v;
        } else {
          const short hi = f2bf(v);
          const int hh = n >> 6, d = n & 63;
          const size_t off = (A.mode == 1) ? ((size_t)(hh * SEQ + m) * 64 + d)
                                           : ((size_t)(hh * 64 + d) * SEQ + m);
          ((short*)A.o0)[off] = hi;
          if (A.o1) {
            const short lo = f2bf(v - bf2f(hi));
            ((short*)A.o1)[off] = lo;
          }
        }
      }
  }
}

// ---------------------------------------------------------------------------
// Flash CoPE attention v4. 256-thr blocks = 4 waves x 16 q-rows (64-q block).
// K/V tiles LDS-staged via DMA (double-buffered, XOR-swizzled). Key tiles
// last->first. CLAMP FAST-PATH: once carry >= 63 (all rows), every remaining
// pos clamps to 63 exactly -> p = exp(s + lis[63]).
// Epilogue writes AO hi/lo planes for the 3-term output GEMM.
// ---------------------------------------------------------------------------
__global__ __launch_bounds__(256, 2)
void cope_attn_mfma(const short* __restrict__ Qhi, const short* __restrict__ Qlo,
                    const short* __restrict__ Khi, const short* __restrict__ Vthi,
                    const short* __restrict__ peT,
                    short* __restrict__ AOhi, short* __restrict__ AOlo) {
  __shared__ __align__(16) short Klds[2][4096];
  __shared__ __align__(16) short Vlds[2][4096];
  __shared__ __align__(16) short Phi[4][16][72];
  __shared__ float2 lis2[4][16][65];
  const int tid = threadIdx.x;
  const int w = tid >> 6, lane = tid & 63;
  const int col = lane & 15, quad = lane >> 4;
  const int h = blockIdx.x & 15;
  const int q0 = (blockIdx.x >> 4) * 64 + w * 16;

  const short* Kb = Khi + (size_t)h * SEQ * 64;
  const short* Vb = Vthi + (size_t)h * 64 * SEQ;

  const int lrow8 = lane >> 3;
  const int src_c = (lane & 7) ^ lrow8;

  auto stage = [&](int kt, int buf) {
#pragma unroll
    for (int i = 0; i < 2; ++i) {
      const int inst = 2 * w + i;
      const int row = inst * 8 + lrow8;
      ASYNC16(Kb + (size_t)(kt * 64 + row) * 64 + src_c * 8, &Klds[buf][inst * 512]);
      ASYNC16(Vb + (size_t)row * SEQ + kt * 64 + src_c * 8, &Vlds[buf][inst * 512]);
    }
  };

  short8 qB[2][2];
#pragma unroll
  for (int ks = 0; ks < 2; ++ks) {
    qB[ks][0] = *(const short8*)(Qhi + (size_t)(h * SEQ + q0 + col) * 64 + ks * 32 + quad * 8);
    qB[ks][1] = *(const short8*)(Qlo + (size_t)(h * SEQ + q0 + col) * 64 + ks * 32 + quad * 8);
  }

  stage(31, 0);

  {
    floatx4 li[4] = {};
#pragma unroll
    for (int nt = 0; nt < 4; ++nt)
#pragma unroll
      for (int ks = 0; ks < 2; ++ks) {
        short8 pb = *(const short8*)(peT + (nt * 16 + col) * 64 + ks * 32 + quad * 8);
        li[nt] = MFMA16(qB[ks][0], pb, li[nt]);
        li[nt] = MFMA16(qB[ks][1], pb, li[nt]);
      }
#pragma unroll
    for (int nt = 0; nt < 4; ++nt)
#pragma unroll
      for (int r = 0; r < 4; ++r) {
        const int qr = quad * 4 + r;
        const int pos = nt * 16 + col;
        const float v = li[nt][r];
        lis2[w][qr][pos].x = v;
        if (pos > 0) lis2[w][qr][pos - 1].y = v;
        if (pos == 63) lis2[w][qr][63].y = v;
      }
  }
  __syncthreads();
  const float lis63 = lis2[w][col][63].x;

  float lrow = 0.f;
  float carry = 0.f;
  bool fast = false;
  floatx4 O[4] = {};

  const int swz = col & 7;

#pragma unroll 1
  for (int it = 0; it < 32; ++it) {
    const int kt = 31 - it;
    const int buf = it & 1;
    if (kt > 0) stage(kt - 1, buf ^ 1);

    short8 kf[4][2], vf[2][4];
#pragma unroll
    for (int ksub = 0; ksub < 4; ++ksub)
#pragma unroll
      for (int ks = 0; ks < 2; ++ks)
        kf[ksub][ks] =
            *(const short8*)&Klds[buf][(ksub * 16 + col) * 64 + (((ks * 4 + quad) ^ swz) * 8)];
#pragma unroll
    for (int ks = 0; ks < 2; ++ks)
#pragma unroll
      for (int dt = 0; dt < 4; ++dt)
        vf[ks][dt] =
            *(const short8*)&Vlds[buf][(dt * 16 + col) * 64 + (((ks * 4 + quad) ^ swz) * 8)];

    floatx4 S[4] = {};
#pragma unroll
    for (int ksub = 0; ksub < 4; ++ksub)
#pragma unroll
      for (int ks = 0; ks < 2; ++ks) {
        S[ksub] = MFMA16(kf[ksub][ks], qB[ks][0], S[ksub]);
        S[ksub] = MFMA16(kf[ksub][ks], qB[ks][1], S[ksub]);
      }
    float sv[4][4];
#pragma unroll
    for (int ksub = 0; ksub < 4; ++ksub)
#pragma unroll
      for (int r = 0; r < 4; ++r) sv[ksub][r] = S[ksub][r] * 0.125f;

    if (!fast && __all((int)(carry >= 63.0f))) fast = true;

    float p4[4][4];
    if (fast) {
#pragma unroll
      for (int ksub = 0; ksub < 4; ++ksub)
#pragma unroll
        for (int r = 0; r < 4; ++r) {
          float pr = __expf(sv[ksub][r] + lis63);
          p4[ksub][r] = pr;
          lrow += pr;
        }
    } else {
      float g[4][4];
#pragma unroll
      for (int ksub = 0; ksub < 4; ++ksub)
#pragma unroll
        for (int r = 0; r < 4; ++r)
          g[ksub][r] = __builtin_amdgcn_rcpf(1.0f + __expf(-sv[ksub][r]));
      float l[4][4], S4[4];
#pragma unroll
      for (int ksub = 0; ksub < 4; ++ksub) {
        l[ksub][3] = g[ksub][3];
        l[ksub][2] = l[ksub][3] + g[ksub][2];
        l[ksub][1] = l[ksub][2] + g[ksub][1];
        l[ksub][0] = l[ksub][1] + g[ksub][0];
        S4[ksub] = l[ksub][0];
      }
      float Sq[4], T[4];
#pragma unroll
      for (int ksub = 0; ksub < 4; ++ksub) {
        float d16 = __shfl_down(S4[ksub], 16, 64);
        float d32 = __shfl_down(S4[ksub], 32, 64);
        float d48 = __shfl_down(S4[ksub], 48, 64);
        float u16 = __shfl_up(S4[ksub], 16, 64);
        float u32 = __shfl_up(S4[ksub], 32, 64);
        float u48 = __shfl_up(S4[ksub], 48, 64);
        float sq = ((quad < 3) ? d16 : 0.f) + ((quad < 2) ? d32 : 0.f) + ((quad < 1) ? d48 : 0.f);
        float pq = ((quad > 0) ? u16 : 0.f) + ((quad > 1) ? u32 : 0.f) + ((quad > 2) ? u48 : 0.f);
        Sq[ksub] = sq;
        T[ksub] = pq + S4[ksub] + sq;
      }
      float U[4];
      U[3] = carry;
      U[2] = U[3] + T[3];
      U[1] = U[2] + T[2];
      U[0] = U[1] + T[1];
      carry = U[0] + T[0];
#pragma unroll
      for (int ksub = 0; ksub < 4; ++ksub)
#pragma unroll
        for (int r = 0; r < 4; ++r) {
          float p = fminf(U[ksub] + Sq[ksub] + l[ksub][r], 63.0f);
          float pf = floorf(p);
          int fi = (int)pf;
          float wq = p - pf;
          float2 lfc = lis2[w][col][fi];
          float pr = __expf(sv[ksub][r] + lfc.x + wq * (lfc.y - lfc.x));
          p4[ksub][r] = pr;
          lrow += pr;
        }
    }
#pragma unroll
    for (int ksub = 0; ksub < 4; ++ksub)
#pragma unroll
      for (int rp = 0; rp < 2; ++rp) {
        short h0 = f2bf(p4[ksub][2 * rp]);
        short h1 = f2bf(p4[ksub][2 * rp + 1]);
        *(int*)&Phi[w][col][ksub * 16 + quad * 4 + 2 * rp] =
            (unsigned short)h0 | ((unsigned)(unsigned short)h1 << 16);
      }
    short8 pa[2];
#pragma unroll
    for (int ks = 0; ks < 2; ++ks)
      pa[ks] = *(const short8*)&Phi[w][col][ks * 32 + quad * 8];
#pragma unroll
    for (int ks = 0; ks < 2; ++ks)
#pragma unroll
      for (int dt = 0; dt < 4; ++dt)
        O[dt] = MFMA16(pa[ks], vf[ks][dt], O[dt]);

    __syncthreads();
  }

  float lr = lrow;
  lr += __shfl_xor(lr, 16, 64);
  lr += __shfl_xor(lr, 32, 64);
  float inv[4];
#pragma unroll
  for (int r = 0; r < 4; ++r) inv[r] = 1.0f / __shfl(lr, quad * 4 + r, 64);
#pragma unroll
  for (int dt = 0; dt < 4; ++dt)
#pragma unroll
    for (int r = 0; r < 4; ++r) {
      float val = O[dt][r] * inv[r];
      int q = q0 + quad * 4 + r;
      int cg = h * 64 + dt * 16 + col;
      short hi = f2bf(val), lo = f2bf(val - bf2f(hi));
      AOhi[(size_t)q * 1024 + cg] = hi;
      AOlo[(size_t)q * 1024 + cg] = lo;
    }
}

// ---------------------------------------------------------------------------
// fp32 fallback (used only if ws_size is too small)
// ---------------------------------------------------------------------------
template <int MODE>
__global__ __launch_bounds__(256)
void gemm_bt_f32(const float* __restrict__ X, const float* __restrict__ W,
                 const float* __restrict__ bias, float* __restrict__ C,
                 int M, int N, int K) {
  __shared__ __align__(16) float Xs[16][68];
  __shared__ __align__(16) float Ws[16][68];
  const int t = threadIdx.x;
  const int tx = t & 15, ty = t >> 4;
  const int m0 = blockIdx.x * 64, n0 = blockIdx.y * 64;
  const int r = t >> 2;
  const int c4 = (t & 3) << 2;
  const float* Xp = X + (size_t)(m0 + r) * K + c4;
  const float* Wp = W + (size_t)(n0 + r) * K + c4;
  float acc[4][4] = {};
  for (int k0 = 0; k0 < K; k0 += 16) {
    float4 xv = *(const float4*)(Xp + k0);
    float4 wv = *(const float4*)(Wp + k0);
    __syncthreads();
    Xs[c4 + 0][r] = xv.x; Xs[c4 + 1][r] = xv.y; Xs[c4 + 2][r] = xv.z; Xs[c4 + 3][r] = xv.w;
    Ws[c4 + 0][r] = wv.x; Ws[c4 + 1][r] = wv.y; Ws[c4 + 2][r] = wv.z; Ws[c4 + 3][r] = wv.w;
    __syncthreads();
#pragma unroll
    for (int k = 0; k < 16; ++k) {
      const float4 xr = *(const float4*)&Xs[k][ty << 2];
      const float4 wr = *(const float4*)&Ws[k][tx << 2];
      const float xa[4] = {xr.x, xr.y, xr.z, xr.w};
      const float wa[4] = {wr.x, wr.y, wr.z, wr.w};
#pragma unroll
      for (int i = 0; i < 4; ++i)
#pragma unroll
        for (int j = 0; j < 4; ++j) acc[i][j] += xa[i] * wa[j];
    }
  }
#pragma unroll
  for (int i = 0; i < 4; ++i) {
    const int m = m0 + (ty << 2) + i;
#pragma unroll
    for (int j = 0; j < 4; ++j) {
      const int n = n0 + (tx << 2) + j;
      const float v = acc[i][j] + bias[n];
      if (MODE == 0) C[(size_t)m * N + n] = v;
      else { const int hh = n >> 6, d = n & 63; C[((size_t)hh * SEQ + m) * HD + d] = v; }
    }
  }
}

__global__ __launch_bounds__(256)
void cope_attn_f32(const float* __restrict__ Qh, const float* __restrict__ Kh,
                   const float* __restrict__ Vh, const float* __restrict__ pe,
                   float* __restrict__ AO) {
  __shared__ float Kt[64][65];
  __shared__ float Vt[64][65];
  __shared__ float lis[16][64];
  const int t = threadIdx.x;
  const int lane = t & 63;
  const int w = t >> 6;
  const int h = blockIdx.y;
  const int qbase = blockIdx.x * 16 + w * 4;
  float qreg[4];
#pragma unroll
  for (int rr = 0; rr < 4; ++rr)
    qreg[rr] = Qh[((size_t)h * SEQ + qbase + rr) * HD + lane];
  float li[4] = {0.f, 0.f, 0.f, 0.f};
  for (int d = 0; d < 64; ++d) {
    const float pv = pe[d * NPOSN + lane];
#pragma unroll
    for (int rr = 0; rr < 4; ++rr) li[rr] += lane_bcast(qreg[rr], d) * pv;
  }
#pragma unroll
  for (int rr = 0; rr < 4; ++rr) lis[w * 4 + rr][lane] = li[rr];
  float mrow[4] = {-1e30f, -1e30f, -1e30f, -1e30f};
  float lrow[4] = {0.f, 0.f, 0.f, 0.f};
  float carry[4] = {0.f, 0.f, 0.f, 0.f};
  float acc[4] = {0.f, 0.f, 0.f, 0.f};
  for (int kt = (SEQ / 64) - 1; kt >= 0; --kt) {
    const int k0 = kt * 64;
    __syncthreads();
#pragma unroll
    for (int i = 0; i < 4; ++i) {
      const int lin = t + i * 256;
      const int row = lin >> 4, cc = (lin & 15) << 2;
      const float4 kv = *(const float4*)(Kh + ((size_t)h * SEQ + k0 + row) * HD + cc);
      Kt[row][cc + 0] = kv.x; Kt[row][cc + 1] = kv.y; Kt[row][cc + 2] = kv.z; Kt[row][cc + 3] = kv.w;
      const float4 vv = *(const float4*)(Vh + ((size_t)h * SEQ + k0 + row) * HD + cc);
      Vt[row][cc + 0] = vv.x; Vt[row][cc + 1] = vv.y; Vt[row][cc + 2] = vv.z; Vt[row][cc + 3] = vv.w;
    }
    __syncthreads();
    float svv[4] = {0.f, 0.f, 0.f, 0.f};
#pragma unroll
    for (int d = 0; d < 64; ++d) {
      const float kd = Kt[lane][d];
#pragma unroll
      for (int rr = 0; rr < 4; ++rr) svv[rr] += lane_bcast(qreg[rr], d) * kd;
    }
    float p4[4], scl[4];
#pragma unroll
    for (int rr = 0; rr < 4; ++rr) {
      const float s = svv[rr] * 0.125f;
      const float gg = 1.0f / (1.0f + __expf(-s));
      float gs = gg;
#pragma unroll
      for (int off = 1; off < 64; off <<= 1) {
        const float tt = __shfl_down(gs, off, 64);
        gs += (lane + off < 64) ? tt : 0.0f;
      }
      const float tot = lane_bcast(gs, 0);
      float p = carry[rr] + gs;
      carry[rr] += tot;
      p = fminf(p, 63.0f);
      const float pf = floorf(p);
      const float wq = p - pf;
      const int fi = (int)pf;
      const int ci = (int)ceilf(p);
      const float cope = lis[w * 4 + rr][ci] * wq + lis[w * 4 + rr][fi] * (1.0f - wq);
      const float av = s + cope;
      float mt = av;
#pragma unroll
      for (int off = 32; off > 0; off >>= 1) mt = fmaxf(mt, __shfl_xor(mt, off, 64));
      const float nm = fmaxf(mrow[rr], mt);
      const float sc = __expf(mrow[rr] - nm);
      const float p2 = __expf(av - nm);
      float psum = p2;
#pragma unroll
      for (int off = 32; off > 0; off >>= 1) psum += __shfl_xor(psum, off, 64);
      lrow[rr] = lrow[rr] * sc + psum;
      mrow[rr] = nm;
      p4[rr] = p2;
      scl[rr] = sc;
    }
#pragma unroll
    for (int rr = 0; rr < 4; ++rr) acc[rr] *= scl[rr];
#pragma unroll
    for (int j = 0; j < 64; ++j) {
      const float vj = Vt[j][lane];
#pragma unroll
      for (int rr = 0; rr < 4; ++rr) acc[rr] += lane_bcast(p4[rr], j) * vj;
    }
  }
#pragma unroll
  for (int rr = 0; rr < 4; ++rr)
    AO[(size_t)(qbase + rr) * ND + h * HD + lane] = acc[rr] / lrow[rr];
}

// ---------------------------------------------------------------------------
extern "C" void kernel_launch(void* const* d_in, const int* in_sizes, int n_in,
                              void* d_out, int out_size, void* d_ws, size_t ws_size,
                              hipStream_t stream) {
  (void)in_sizes; (void)n_in; (void)out_size;
  const float* q    = (const float*)d_in[0];
  const float* k    = (const float*)d_in[1];
  const float* v    = (const float*)d_in[2];
  const float* Wq_w = (const float*)d_in[3];
  const float* Wq_b = (const float*)d_in[4];
  const float* Wk_w = (const float*)d_in[5];
  const float* Wk_b = (const float*)d_in[6];
  const float* Wv_w = (const float*)d_in[7];
  const float* Wv_b = (const float*)d_in[8];
  const float* Wo_w = (const float*)d_in[9];
  const float* Wo_b = (const float*)d_in[10];
  const float* pe   = (const float*)d_in[11];
  float* out = (float*)d_out;
  char* ws = (char*)d_ws;

  const size_t XP = (size_t)SEQ * 1024 * 2;   // 4 MB per activation plane
  const size_t WP = (size_t)1024 * 1024 * 2;  // 2 MB per weight plane
  const size_t HB = (size_t)SEQ * 1024 * 2;   // 4 MB per head buffer
  const size_t NEED = 6 * XP + 8 * WP + 4 * HB + 8192;

  if (ws_size >= NEED) {
    short* Xqh = (short*)ws;               short* Xql = (short*)(ws + XP);
    short* Xkh = (short*)(ws + 2 * XP);    short* Xkl = (short*)(ws + 3 * XP);
    short* Xvh = (short*)(ws + 4 * XP);    short* Xvl = (short*)(ws + 5 * XP);
    char*  wb  = ws + 6 * XP;
    short* Wqh = (short*)wb;               short* Wql = (short*)(wb + WP);
    short* Wkh = (short*)(wb + 2 * WP);    short* Wkl = (short*)(wb + 3 * WP);
    short* Wvh = (short*)(wb + 4 * WP);    short* Wvl = (short*)(wb + 5 * WP);
    short* Woh = (short*)(wb + 6 * WP);    short* Wol = (short*)(wb + 7 * WP);
    char*  hb  = wb + 8 * WP;
    short* Qhi = (short*)hb;               short* Qlo = (short*)(hb + HB);
    short* Khi = (short*)(hb + 2 * HB);    short* Vthi = (short*)(hb + 3 * HB);
    short* peT = (short*)(hb + 4 * HB);
    short* AOhi = Xqh;                     // reuse after projections
    short* AOlo = Xql;

    Prep2 P{q, Xqh, Xql, k, Xkh, Xkl, v, Xvh, Xvl,
            Wq_w, Wqh, Wql, Wk_w, Wkh, Wkl, Wv_w, Wvh, Wvl, Wo_w, Woh, Wol,
            pe, peT};
    prep2<<<dim3(2048, 1, 8), 256, 0, stream>>>(P);
    GArg2 aq{Xqh, Xql, Wqh, Wql, Wq_b, Qhi, Qlo, 1};     // 3-term (Q consumed split)
    GArg2 ak{Xkh, Xkl, Wkh, nullptr, Wk_b, Khi, nullptr, 1};   // 2-term, hi only
    GArg2 av{Xvh, Xvl, Wvh, nullptr, Wv_b, Vthi, nullptr, 2};  // 2-term, hi only, transposed
    gemm_planes<<<dim3(16, 16, 3), 256, 0, stream>>>(aq, ak, av);
    cope_attn_mfma<<<512, 256, 0, stream>>>(Qhi, Qlo, Khi, Vthi, peT, AOhi, AOlo);
    GArg2 ao{AOhi, AOlo, Woh, Wol, Wo_b, (void*)out, nullptr, 0};   // 3-term fp32 out
    gemm_planes<<<dim3(16, 16, 1), 256, 0, stream>>>(ao, ao, ao);
  } else {
    const size_t per = (size_t)NH * SEQ * HD;
    float* Qh = (float*)d_ws;
    float* Kh = Qh + per;
    float* Vh = Kh + per;
    float* AO = Vh + per;
    dim3 gblk(256), ggrd(SEQ / 64, ND / 64);
    gemm_bt_f32<1><<<ggrd, gblk, 0, stream>>>(q, Wq_w, Wq_b, Qh, SEQ, ND, ND);
    gemm_bt_f32<1><<<ggrd, gblk, 0, stream>>>(k, Wk_w, Wk_b, Kh, SEQ, ND, ND);
    gemm_bt_f32<1><<<ggrd, gblk, 0, stream>>>(v, Wv_w, Wv_b, Vh, SEQ, ND, ND);
    cope_attn_f32<<<dim3(SEQ / 16, NH), 256, 0, stream>>>(Qh, Kh, Vh, pe, AO);
    gemm_bt_f32<0><<<ggrd, gblk, 0, stream>>>(AO, Wo_w, Wo_b, out, SEQ, ND, ND);
  }
}